// Round 14
// baseline (566.320 us; speedup 1.0000x reference)
//
#include <hip/hip_runtime.h>
#include <math.h>

#define DEV __device__ __forceinline__

static const int N_LOW = 5000, N_HIGH = 50000, E_LH = 200000, E_HH = 400000;
static const int E2 = E_HH + N_HIGH;   // 450000 with self loops
static const int ETOT = E_LH + E2;     // 650000 combined
static const int RBLK = 2048;          // bn stage-1 blocks

typedef __attribute__((ext_vector_type(8))) short bf16x8;
typedef __attribute__((ext_vector_type(4))) float f32x4;
typedef __attribute__((ext_vector_type(8))) unsigned short u16x8;
typedef unsigned short u16;

DEV short f2bf(float v) {            // round-to-nearest-even f32 -> bf16
    unsigned u = __float_as_uint(v);
    u += 0x7FFFu + ((u >> 16) & 1u);
    return (short)(u >> 16);
}
DEV float bf2f(u16 u) { return __uint_as_float(((unsigned)u) << 16); }

template <int VPL> struct RawTT { using T = u16; };
template <> struct RawTT<4> { using T = ushort4; };

// =================== MFMA GEMM on fragment-ordered operands =================
// DOTM: 0 = none, 1 = direct per-head row-dot store (head = blockIdx.x),
//       2 = atomicAdd partial row-dot (head spans multiple blocks).
template <bool RELU, bool BF16OUT, int DOTM>
DEV void gemm_body(const bf16x8* __restrict__ Af, const bf16x8* __restrict__ Bf,
                   const float* __restrict__ bias, float* __restrict__ C,
                   int M, int N, int nkt,
                   const float* __restrict__ att, float* __restrict__ dout,
                   int Hh) {
    const int l = threadIdx.x & 63;
    const int w = threadIdx.x >> 6;
    const int nt0 = blockIdx.x * 4;
    const int mt0 = blockIdx.y * 8 + w * 2;
    f32x4 acc[2][4];
#pragma unroll
    for (int i = 0; i < 2; i++)
#pragma unroll
        for (int j = 0; j < 4; j++) acc[i][j] = (f32x4){0.f, 0.f, 0.f, 0.f};
    const bf16x8* a0p = Af + (size_t)mt0 * nkt * 64 + l;
    const bf16x8* a1p = a0p + (size_t)nkt * 64;
    const bf16x8* bp = Bf + (size_t)nt0 * nkt * 64 + l;
    for (int kt = 0; kt < nkt; kt++) {
        bf16x8 a0 = a0p[kt * 64];
        bf16x8 a1 = a1p[kt * 64];
        bf16x8 b0 = bp[kt * 64];
        bf16x8 b1 = bp[(size_t)(nkt + kt) * 64];
        bf16x8 b2 = bp[(size_t)(2 * nkt + kt) * 64];
        bf16x8 b3 = bp[(size_t)(3 * nkt + kt) * 64];
        acc[0][0] = __builtin_amdgcn_mfma_f32_16x16x32_bf16(a0, b0, acc[0][0], 0, 0, 0);
        acc[0][1] = __builtin_amdgcn_mfma_f32_16x16x32_bf16(a0, b1, acc[0][1], 0, 0, 0);
        acc[0][2] = __builtin_amdgcn_mfma_f32_16x16x32_bf16(a0, b2, acc[0][2], 0, 0, 0);
        acc[0][3] = __builtin_amdgcn_mfma_f32_16x16x32_bf16(a0, b3, acc[0][3], 0, 0, 0);
        acc[1][0] = __builtin_amdgcn_mfma_f32_16x16x32_bf16(a1, b0, acc[1][0], 0, 0, 0);
        acc[1][1] = __builtin_amdgcn_mfma_f32_16x16x32_bf16(a1, b1, acc[1][1], 0, 0, 0);
        acc[1][2] = __builtin_amdgcn_mfma_f32_16x16x32_bf16(a1, b2, acc[1][2], 0, 0, 0);
        acc[1][3] = __builtin_amdgcn_mfma_f32_16x16x32_bf16(a1, b3, acc[1][3], 0, 0, 0);
    }
    const int colb = nt0 * 16 + (l & 15);
    const int rsub = (l >> 4) * 4;
    float attc[4];
    float ds[2][4];
    if constexpr (DOTM != 0) {
#pragma unroll
        for (int n = 0; n < 4; n++) attc[n] = att[colb + n * 16];
#pragma unroll
        for (int i = 0; i < 2; i++)
#pragma unroll
            for (int j = 0; j < 4; j++) ds[i][j] = 0.f;
    }
#pragma unroll
    for (int mi = 0; mi < 2; mi++) {
        int rowb = (mt0 + mi) * 16 + rsub;
#pragma unroll
        for (int r = 0; r < 4; r++) {
            int row = rowb + r;
            if (row >= M) continue;
#pragma unroll
            for (int n = 0; n < 4; n++) {
                int col = colb + n * 16;
                float v = acc[mi][n][r] + bias[col];
                if (RELU) v = fmaxf(v, 0.f);
                if (BF16OUT) {
                    u16 q = (u16)f2bf(v);
                    ((u16*)C)[(size_t)row * N + col] = q;
                    if constexpr (DOTM != 0)
                        ds[mi][r] = fmaf(bf2f(q), attc[n], ds[mi][r]);
                } else {
                    C[(size_t)row * N + col] = v;
                }
            }
        }
    }
    if constexpr (DOTM != 0) {
#pragma unroll
        for (int mi = 0; mi < 2; mi++) {
#pragma unroll
            for (int r = 0; r < 4; r++) {
                float dsv = ds[mi][r];
                dsv += __shfl_xor(dsv, 1, 64);
                dsv += __shfl_xor(dsv, 2, 64);
                dsv += __shfl_xor(dsv, 4, 64);
                dsv += __shfl_xor(dsv, 8, 64);
                int row = (mt0 + mi) * 16 + rsub + r;
                if ((l & 15) == 0 && row < M) {
                    if (DOTM == 1)
                        dout[(size_t)row * Hh + blockIdx.x] = dsv;
                    else
                        atomicAdd(&dout[row], dsv);
                }
            }
        }
    }
}

__global__ __launch_bounds__(256) void gemm_plain(
    const bf16x8* __restrict__ Af, const bf16x8* __restrict__ Bf,
    const float* __restrict__ bias, float* __restrict__ C,
    int M, int N, int nkt) {
    gemm_body<true, false, 0>(Af, Bf, bias, C, M, N, nkt, nullptr, nullptr, 0);
}

// d-layer GEMM: bf16 out + atomic row-dot (head spans 4 blocks)
__global__ __launch_bounds__(256) void gemm_dlayer(
    const bf16x8* __restrict__ Af, const bf16x8* __restrict__ Bf,
    const float* __restrict__ bias, float* __restrict__ C,
    int M, int N, int nkt, const float* __restrict__ att,
    float* __restrict__ dout) {
    gemm_body<false, true, 2>(Af, Bf, bias, C, M, N, nkt, att, dout, 1);
}

// paired variant: z selects (Bf0,bias0,C0,dl) or (Bf1,bias1,C1,dr); same A/att.
__global__ __launch_bounds__(256) void gemm_mfma2(
    const bf16x8* __restrict__ Af,
    const bf16x8* __restrict__ Bf0, const bf16x8* __restrict__ Bf1,
    const float* __restrict__ bias0, const float* __restrict__ bias1,
    float* __restrict__ C0, float* __restrict__ C1,
    int M, int N, int nkt, const float* __restrict__ att,
    float* __restrict__ dl, float* __restrict__ dr, int Hh) {
    if (blockIdx.z == 0)
        gemm_body<false, true, 1>(Af, Bf0, bias0, C0, M, N, nkt, att, dl, Hh);
    else
        gemm_body<false, true, 1>(Af, Bf1, bias1, C1, M, N, nkt, att, dr, Hh);
}

// --------- BN-apply (stats from raw sums) + (relu) + bf16 frag cast --------
template <bool RELU>
__global__ __launch_bounds__(256) void bn_frag(
    const u16* __restrict__ x, int Nrows, int F, int STR, int SS,
    const float* __restrict__ sums,
    const float* __restrict__ g, const float* __restrict__ b,
    bf16x8* __restrict__ Af, int nmt, int nkt) {
    int total = nmt * nkt * 64;
    for (int idx = blockIdx.x * blockDim.x + threadIdx.x; idx < total;
         idx += gridDim.x * blockDim.x) {
        int mt = idx / (nkt * 64);
        int rem = idx - mt * (nkt * 64);
        int kt = rem >> 6, l = rem & 63;
        int row = mt * 16 + (l & 15);
        int colb = kt * 32 + (l >> 4) * 8;
        bf16x8 o;
#pragma unroll
        for (int j = 0; j < 8; j++) {
            int col = colb + j;
            float v = 0.f;
            if (row < Nrows && col < F) {
                float mu = sums[col] / Nrows;
                float var = sums[SS + col] / Nrows - mu * mu;
                float istd = rsqrtf(fmaxf(var, 0.f) + 1e-5f);
                v = (bf2f(x[(size_t)row * STR + col]) - mu) * istd * g[col] + b[col];
                if (RELU) v = fmaxf(v, 0.f);
            }
            o[j] = f2bf(v);
        }
        Af[idx] = o;
    }
}

// --------- plain cast (xl f32) into fragment-ordered A, zero-padded --------
__global__ __launch_bounds__(256) void cast_frag(
    const float* __restrict__ x, int Nrows, int F,
    bf16x8* __restrict__ Af, int nmt, int nkt) {
    int total = nmt * nkt * 64;
    for (int idx = blockIdx.x * blockDim.x + threadIdx.x; idx < total;
         idx += gridDim.x * blockDim.x) {
        int mt = idx / (nkt * 64);
        int rem = idx - mt * (nkt * 64);
        int kt = rem >> 6, l = rem & 63;
        int row = mt * 16 + (l & 15);
        int colb = kt * 32 + (l >> 4) * 8;
        bf16x8 o;
#pragma unroll
        for (int j = 0; j < 8; j++) {
            int col = colb + j;
            o[j] = (row < Nrows && col < F) ? f2bf(x[(size_t)row * F + col]) : (short)0;
        }
        Af[idx] = o;
    }
}

// --------- ALL weight [K][N] -> fragment-ordered B transforms in one -------
struct WtJobs {
    const float* W[8];
    bf16x8* out[8];
    int K[8], Nn[8], nnt[8], nkt[8];
};
__global__ __launch_bounds__(256) void wt_frag_all(WtJobs jobs) {
    const int job = blockIdx.y;
    const float* W = jobs.W[job];
    bf16x8* Bf = jobs.out[job];
    const int K = jobs.K[job], N = jobs.Nn[job];
    const int nkt = jobs.nkt[job];
    int total = jobs.nnt[job] * nkt * 64;
    for (int idx = blockIdx.x * blockDim.x + threadIdx.x; idx < total;
         idx += gridDim.x * blockDim.x) {
        int nt = idx / (nkt * 64);
        int rem = idx - nt * (nkt * 64);
        int kt = rem >> 6, l = rem & 63;
        int col = nt * 16 + (l & 15);
        int kb = kt * 32 + (l >> 4) * 8;
        bf16x8 o;
#pragma unroll
        for (int j = 0; j < 8; j++) {
            int k = kb + j;
            o[j] = (k < K && col < N) ? f2bf(W[(size_t)k * N + col]) : (short)0;
        }
        Bf[idx] = o;
    }
}

// ------------- combined CSR build over BOTH edge sets ----------------------
__global__ __launch_bounds__(256) void hist_all(
    const int* __restrict__ di_lh, const int* __restrict__ di_hh,
    int* __restrict__ cnt) {
    for (int i = blockIdx.x * blockDim.x + threadIdx.x; i < ETOT;
         i += gridDim.x * blockDim.x) {
        if (i < E_LH) {
            atomicAdd(&cnt[di_lh[i]], 1);
        } else {
            int j = i - E_LH;
            int d = (j < E_HH) ? di_hh[j] : (j - E_HH);
            atomicAdd(&cnt[N_HIGH + d], 1);
        }
    }
}

// ---- parallel exclusive scan over n ints (3 kernels, chunks of 1024) -------
__global__ __launch_bounds__(256) void scan_partial(
    const int* __restrict__ cnt, int* __restrict__ off,
    int* __restrict__ bsum, int n) {
    __shared__ int s[256];
    const int t = threadIdx.x;
    const int base = blockIdx.x * 1024 + t * 4;
    int v0 = (base < n) ? cnt[base] : 0;
    int v1 = (base + 1 < n) ? cnt[base + 1] : 0;
    int v2 = (base + 2 < n) ? cnt[base + 2] : 0;
    int v3 = (base + 3 < n) ? cnt[base + 3] : 0;
    int tsum = v0 + v1 + v2 + v3;
    s[t] = tsum;
    __syncthreads();
    for (int step = 1; step < 256; step <<= 1) {
        int q = (t >= step) ? s[t - step] : 0;
        __syncthreads();
        s[t] += q;
        __syncthreads();
    }
    int excl = s[t] - tsum;
    if (base < n) off[base] = excl;
    if (base + 1 < n) off[base + 1] = excl + v0;
    if (base + 2 < n) off[base + 2] = excl + v0 + v1;
    if (base + 3 < n) off[base + 3] = excl + v0 + v1 + v2;
    if (t == 255) bsum[blockIdx.x] = s[255];
}

__global__ __launch_bounds__(256) void scan_bsums(
    int* __restrict__ bsum, int nb, int* __restrict__ off, int n) {
    __shared__ int s[256];
    const int t = threadIdx.x;
    int v = (t < nb) ? bsum[t] : 0;
    s[t] = v;
    __syncthreads();
    for (int step = 1; step < 256; step <<= 1) {
        int q = (t >= step) ? s[t - step] : 0;
        __syncthreads();
        s[t] += q;
        __syncthreads();
    }
    if (t < nb) bsum[t] = s[t] - v;          // exclusive
    if (t == 255) off[n] = s[255];           // grand total
}

__global__ __launch_bounds__(256) void scan_add(
    int* __restrict__ off, const int* __restrict__ bsum, int n) {
    int b = blockIdx.x;
    int add = bsum[b];
    int base = b * 1024;
    int end = base + 1024 < n ? base + 1024 : n;
    for (int i = base + threadIdx.x; i < end; i += 256) off[i] += add;
}

__global__ __launch_bounds__(256) void scatter_all(
    const int* __restrict__ si_lh, const int* __restrict__ di_lh,
    const int* __restrict__ si_hh, const int* __restrict__ di_hh,
    int* __restrict__ cur, int* __restrict__ csr) {
    for (int i = blockIdx.x * blockDim.x + threadIdx.x; i < ETOT;
         i += gridDim.x * blockDim.x) {
        int d, s, bucket;
        if (i < E_LH) {
            d = di_lh[i]; s = si_lh[i]; bucket = d;
        } else {
            int j = i - E_LH;
            if (j < E_HH) { d = di_hh[j]; s = si_hh[j]; }
            else { d = s = j - E_HH; }
            bucket = N_HIGH + d;
        }
        int p = atomicAdd(&cur[bucket], 1);
        csr[p] = s;
    }
}

// ---------- fused GATv2: lrelu decomposition + defer-max online softmax ----
// logit = 0.6*(dl[src]+dr[dst]) + 0.4*sum(|hl+hr|*att)   (exact identity)
template <int H, int C, bool HR_ONFLY>
__global__ __launch_bounds__(256) void gat_gather(
    const u16* __restrict__ hl, const u16* __restrict__ hr,
    const float* __restrict__ xh, const float* __restrict__ Wr,
    const float* __restrict__ br,
    const float* __restrict__ dl, const float* __restrict__ drt,
    const int* __restrict__ rowptr, const int* __restrict__ csr_src,
    const float* __restrict__ att, const float* __restrict__ bias,
    u16* __restrict__ out, int outStride, int outOfs, int Ndst,
    const float* __restrict__ col0) {
    constexpr int HC = H * C;
    constexpr int VPL = HC / 64;
    constexpr int LPH = C / VPL;
    using RawT = typename RawTT<VPL>::T;
    int w = blockIdx.x * (blockDim.x >> 6) + (threadIdx.x >> 6);
    if (w >= Ndst) return;
    const int l = threadIdx.x & 63;
    const int h = (l * VPL) / C;

    float hrv[VPL], attv[VPL];
    float drv;
    if constexpr (HR_ONFLY) {
        static_assert(!HR_ONFLY || VPL == 4, "onfly assumes VPL==4");
        float xv = xh[w];
        float4 wr = *reinterpret_cast<const float4*>(Wr + l * 4);
        float4 bb = *reinterpret_cast<const float4*>(br + l * 4);
        hrv[0] = fmaf(xv, wr.x, bb.x); hrv[1] = fmaf(xv, wr.y, bb.y);
        hrv[2] = fmaf(xv, wr.z, bb.z); hrv[3] = fmaf(xv, wr.w, bb.w);
        float4 u = *reinterpret_cast<const float4*>(att + l * 4);
        attv[0] = u.x; attv[1] = u.y; attv[2] = u.z; attv[3] = u.w;
        float p = 0.f;
#pragma unroll
        for (int j = 0; j < 4; j++) p = fmaf(hrv[j], attv[j], p);
#pragma unroll
        for (int t2 = 1; t2 < LPH; t2 <<= 1) p += __shfl_xor(p, t2, 64);
        drv = p;
    } else if constexpr (VPL == 4) {
        ushort4 t = *(reinterpret_cast<const ushort4*>(hr + (size_t)w * HC) + l);
        hrv[0] = bf2f(t.x); hrv[1] = bf2f(t.y); hrv[2] = bf2f(t.z); hrv[3] = bf2f(t.w);
        float4 u = *reinterpret_cast<const float4*>(att + l * 4);
        attv[0] = u.x; attv[1] = u.y; attv[2] = u.z; attv[3] = u.w;
        drv = drt[(size_t)w * H + h];
    } else {
#pragma unroll
        for (int j = 0; j < VPL; j++) {
            hrv[j] = bf2f(hr[(size_t)w * HC + l * VPL + j]);
            attv[j] = att[l * VPL + j];
        }
        drv = drt[(size_t)w * H + h];
    }

    const int e0 = rowptr[w], e1 = rowptr[w + 1];
    float m = -3.4e38f, s = 0.f;
    float acc[VPL] = {};

    auto ldraw = [&](int sv) -> RawT {
        if constexpr (VPL == 4)
            return *(reinterpret_cast<const ushort4*>(hl + (size_t)sv * HC) + l);
        else
            return hl[(size_t)sv * HC + l];
    };
    auto proc = [&](RawT t, float dlv) {
        float hlv[VPL];
        if constexpr (VPL == 4) {
            hlv[0] = bf2f(t.x); hlv[1] = bf2f(t.y);
            hlv[2] = bf2f(t.z); hlv[3] = bf2f(t.w);
        } else {
            hlv[0] = bf2f(t);
        }
        float red = 0.f;
#pragma unroll
        for (int j = 0; j < VPL; j++) {
            float z = hlv[j] + hrv[j];
            red = fmaf(fabsf(z), attv[j], red);   // abs = free input modifier
        }
#pragma unroll
        for (int t2 = 1; t2 < LPH; t2 <<= 1) red += __shfl_xor(red, t2, 64);
        float v = fmaf(0.4f, red, 0.6f * (dlv + drv));
        float dd = v - m;
        if (__any(dd > 8.f)) {           // rare: max moved by > threshold
            bool up = dd > 8.f;
            float arg = up ? -dd : dd;
            float ef = __expf(arg);
            float sc = up ? ef : 1.f;
            float p  = up ? 1.f : ef;
            m = up ? v : m;
            s = fmaf(s, sc, p);
#pragma unroll
            for (int j = 0; j < VPL; j++) acc[j] = fmaf(acc[j], sc, p * hlv[j]);
        } else {                          // common: no rescale needed
            float p = __expf(dd);
            s += p;
#pragma unroll
            for (int j = 0; j < VPL; j++) acc[j] = fmaf(p, hlv[j], acc[j]);
        }
    };

    int e = e0;
    for (; e + 3 < e1; e += 4) {
        int sv0 = csr_src[e];
        int sv1 = csr_src[e + 1];
        int sv2 = csr_src[e + 2];
        int sv3 = csr_src[e + 3];
        RawT t0 = ldraw(sv0);
        RawT t1 = ldraw(sv1);
        RawT t2 = ldraw(sv2);
        RawT t3 = ldraw(sv3);
        float d0 = dl[(size_t)sv0 * H + h];
        float d1 = dl[(size_t)sv1 * H + h];
        float d2 = dl[(size_t)sv2 * H + h];
        float d3 = dl[(size_t)sv3 * H + h];
        proc(t0, d0); proc(t1, d1); proc(t2, d2); proc(t3, d3);
    }
    for (; e < e1; e++) {
        int sv = csr_src[e];
        RawT t = ldraw(sv);
        float dv = dl[(size_t)sv * H + h];
        proc(t, dv);
    }

    float inv = 1.f / (s + 1e-16f);
    float dnorm = inv / fmaxf((float)(e1 - e0), 1.f);
    if constexpr (VPL == 4) {
        if (((outOfs | outStride) & 3) == 0) {
            ushort4 o;
            o.x = (u16)f2bf(acc[0] * dnorm + bias[l * 4 + 0]);
            o.y = (u16)f2bf(acc[1] * dnorm + bias[l * 4 + 1]);
            o.z = (u16)f2bf(acc[2] * dnorm + bias[l * 4 + 2]);
            o.w = (u16)f2bf(acc[3] * dnorm + bias[l * 4 + 3]);
            *(reinterpret_cast<ushort4*>(out + (size_t)w * outStride + outOfs) + l) = o;
        } else {
#pragma unroll
            for (int j = 0; j < 4; j++)
                out[(size_t)w * outStride + outOfs + l * 4 + j] =
                    (u16)f2bf(acc[j] * dnorm + bias[l * 4 + j]);
        }
    } else {
#pragma unroll
        for (int j = 0; j < VPL; j++)
            out[(size_t)w * outStride + outOfs + l * VPL + j] =
                (u16)f2bf(acc[j] * dnorm + bias[l * VPL + j]);
    }
    if (col0 && l == 0) out[(size_t)w * outStride] = (u16)f2bf(col0[w]);
}

// ----------- BN stats stage 1: ushort8 loads, LDS reduce, no atomics -------
template <int NC, int RPB>
__global__ __launch_bounds__(256) void bn_partial3(
    const u16* __restrict__ x, int Nrows, float* __restrict__ partials) {
    constexpr int STR = NC * 8;
    constexpr int NSTAT = 2 * NC * 8;
    const int t = threadIdx.x;
    const int b = blockIdx.x;
    __shared__ float l1[NC * RPB * 8];
    __shared__ float l2[NC * RPB * 8];
    float s1[8] = {}, s2[8] = {};
    if (t < NC * RPB) {
        const int rg = t / NC, cg = t - (t / NC) * NC;
        for (int r = b * RPB + rg; r < Nrows; r += RBLK * RPB) {
            u16x8 p = *reinterpret_cast<const u16x8*>(x + (size_t)r * STR + cg * 8);
#pragma unroll
            for (int j = 0; j < 8; j++) {
                float v = bf2f(p[j]);
                s1[j] += v; s2[j] += v * v;
            }
        }
#pragma unroll
        for (int j = 0; j < 8; j++) {
            l1[t * 8 + j] = s1[j];
            l2[t * 8 + j] = s2[j];
        }
    }
    __syncthreads();
    if (t < NC) {
        float a[8] = {}, c[8] = {};
#pragma unroll
        for (int rg = 0; rg < RPB; rg++)
#pragma unroll
            for (int j = 0; j < 8; j++) {
                a[j] += l1[(rg * NC + t) * 8 + j];
                c[j] += l2[(rg * NC + t) * 8 + j];
            }
#pragma unroll
        for (int j = 0; j < 8; j++) {
            partials[(size_t)b * NSTAT + t * 8 + j] = a[j];
            partials[(size_t)b * NSTAT + NC * 8 + t * 8 + j] = c[j];
        }
    }
}

// ----------- BN stats stage 2: 2D grid, coalesced, few atomics -------------
__global__ __launch_bounds__(256) void bn_reduce2(
    const float* __restrict__ partials, int nstat, float* __restrict__ bsum) {
    const int sl = threadIdx.x & 63, ch = threadIdx.x >> 6;
    const int s = blockIdx.x * 64 + sl;
    const int b0 = blockIdx.y * (RBLK / 32);
    float v = 0.f;
    if (s < nstat) {
        for (int b = b0 + ch; b < b0 + RBLK / 32; b += 4)
            v += partials[(size_t)b * nstat + s];
    }
    __shared__ float l[256];
    l[threadIdx.x] = v;
    __syncthreads();
    if (ch == 0 && s < nstat)
        atomicAdd(&bsum[s], l[sl] + l[sl + 64] + l[sl + 128] + l[sl + 192]);
}

// y[i] = dot64(hid[i], W2) + b2
__global__ __launch_bounds__(256) void dot_w2(const float* __restrict__ hid,
                                              const float* __restrict__ W2,
                                              const float* __restrict__ b2,
                                              float* __restrict__ y, int N) {
    int w = blockIdx.x * (blockDim.x >> 6) + (threadIdx.x >> 6);
    int l = threadIdx.x & 63;
    if (w >= N) return;
    float v = hid[(size_t)w * 64 + l] * W2[l];
#pragma unroll
    for (int m = 1; m < 64; m <<= 1) v += __shfl_xor(v, m, 64);
    if (l == 0) y[w] = v + b2[0];
}

// ---------------------------------------------------------------------------
extern "C" void kernel_launch(void* const* d_in, const int* in_sizes, int n_in,
                              void* d_out, int out_size, void* d_ws, size_t ws_size,
                              hipStream_t stream) {
    const float* xl   = (const float*)d_in[0];
    const float* xh   = (const float*)d_in[1];
    const float* zstd = (const float*)d_in[2];
    const int* si_lh  = (const int*)d_in[3];
    const int* di_lh  = (const int*)d_in[4];
    const int* si_hh  = (const int*)d_in[5];
    const int* di_hh  = (const int*)d_in[6];
    int a = 7;
    const float *d_Wl = (const float*)d_in[a++], *d_bl = (const float*)d_in[a++],
                *d_Wr = (const float*)d_in[a++], *d_br = (const float*)d_in[a++],
                *d_att = (const float*)d_in[a++], *d_b = (const float*)d_in[a++];
    const float *p1_Wl = (const float*)d_in[a++], *p1_bl = (const float*)d_in[a++],
                *p1_Wr = (const float*)d_in[a++], *p1_br = (const float*)d_in[a++],
                *p1_att = (const float*)d_in[a++], *p1_b = (const float*)d_in[a++];
    const float *p2_Wl = (const float*)d_in[a++], *p2_bl = (const float*)d_in[a++],
                *p2_Wr = (const float*)d_in[a++], *p2_br = (const float*)d_in[a++],
                *p2_att = (const float*)d_in[a++], *p2_b = (const float*)d_in[a++];
    const float *p3_Wl = (const float*)d_in[a++], *p3_bl = (const float*)d_in[a++],
                *p3_Wr = (const float*)d_in[a++], *p3_br = (const float*)d_in[a++],
                *p3_att = (const float*)d_in[a++], *p3_b = (const float*)d_in[a++];
    const float *bn0_g = (const float*)d_in[a++], *bn0_b = (const float*)d_in[a++],
                *bn1_g = (const float*)d_in[a++], *bn1_b = (const float*)d_in[a++],
                *bn2_g = (const float*)d_in[a++], *bn2_b = (const float*)d_in[a++],
                *bn3_g = (const float*)d_in[a++], *bn3_b = (const float*)d_in[a++];
    const float *pr_W1 = (const float*)d_in[a++], *pr_b1 = (const float*)d_in[a++],
                *pr_W2 = (const float*)d_in[a++], *pr_b2 = (const float*)d_in[a++];
    float* y = (float*)d_out;

    const int N = N_HIGH;
    const int NMT = 3125;                    // 50000/16
    const int NB2 = (2 * N + 1023) / 1024;   // scan blocks over 2N = 98
    // ---- workspace layout ----
    float* ws = (float*)d_ws;
    float* xA = ws;                           // region 50000*257 f32 (bf16 stride-264 used / hosts AfA)
    float* xB = xA + (size_t)N * 257;         // region 50000*256 f32 (bf16 used / hosts AfB)
    float* hl = xB + (size_t)N * 256;         // 50000*256 (bf16 used)
    float* hr = hl + (size_t)N * 256;         // 50000*256 (bf16 used; dead during BN -> partials)
    bf16x8* xl_f = (bf16x8*)(hr + (size_t)N * 256);   // 320*4*64 frags
    bf16x8* wf_d   = xl_f + 320 * 4 * 64;     // 16*4*64
    bf16x8* wf_p1l = wf_d + 16 * 4 * 64;      // 16*9*64
    bf16x8* wf_p1r = wf_p1l + 16 * 9 * 64;
    bf16x8* wf_p2l = wf_p1r + 16 * 9 * 64;    // 16*8*64
    bf16x8* wf_p2r = wf_p2l + 16 * 8 * 64;
    bf16x8* wf_p3l = wf_p2r + 16 * 8 * 64;    // 4*8*64
    bf16x8* wf_p3r = wf_p3l + 4 * 8 * 64;
    bf16x8* wf_pr1 = wf_p3r + 4 * 8 * 64;     // 4*2*64
    float* bsum = (float*)(wf_pr1 + 4 * 2 * 64); // 544
    int* bscan  = (int*)(bsum + 544);         // 256
    int* cnt    = bscan + 256;                // 2N
    int* off    = cnt + 2 * N;                // 2N+1
    int* cur    = off + 2 * N + 1;            // 2N
    int* csr    = cur + 2 * N;                // 650000
    float* dl   = (float*)(csr + ETOT);       // 200000 (N*H max)
    float* dr   = dl + 200000;                // 200000
    float* dl_d = dr + 200000;                // 5000 (d-layer, atomic)
    size_t need = (size_t)((char*)(dl_d + N_LOW) - (char*)ws);
    if (ws_size < need) return;
    bf16x8* AfB = (bf16x8*)xB;
    bf16x8* AfA = (bf16x8*)xA;
    u16* xA16 = (u16*)xA;        // stride-264 bf16 rows
    u16* xB16 = (u16*)xB;
    u16* hl16 = (u16*)hl;
    u16* hr16 = (u16*)hr;
    float* partials = hr;        // overlay: hr region dead during BN stats
    int* rp_lh = off;
    int* rp_hh = off + N;

    dim3 blk(256);
    auto wgrid = [](int E) { return dim3((E + 3) / 4); };
    auto egrid = [](size_t total) {
        size_t g = (total + 255) / 256;
        return dim3((unsigned)(g > 2048 ? 2048 : g));
    };

    // ===================== weight fragment transforms (one kernel) ==========
    WtJobs jobs;
    jobs.W[0] = d_Wl;  jobs.out[0] = wf_d;   jobs.K[0] = 125; jobs.Nn[0] = 256; jobs.nnt[0] = 16; jobs.nkt[0] = 4;
    jobs.W[1] = p1_Wl; jobs.out[1] = wf_p1l; jobs.K[1] = 257; jobs.Nn[1] = 256; jobs.nnt[1] = 16; jobs.nkt[1] = 9;
    jobs.W[2] = p1_Wr; jobs.out[2] = wf_p1r; jobs.K[2] = 257; jobs.Nn[2] = 256; jobs.nnt[2] = 16; jobs.nkt[2] = 9;
    jobs.W[3] = p2_Wl; jobs.out[3] = wf_p2l; jobs.K[3] = 256; jobs.Nn[3] = 256; jobs.nnt[3] = 16; jobs.nkt[3] = 8;
    jobs.W[4] = p2_Wr; jobs.out[4] = wf_p2r; jobs.K[4] = 256; jobs.Nn[4] = 256; jobs.nnt[4] = 16; jobs.nkt[4] = 8;
    jobs.W[5] = p3_Wl; jobs.out[5] = wf_p3l; jobs.K[5] = 256; jobs.Nn[5] = 64;  jobs.nnt[5] = 4;  jobs.nkt[5] = 8;
    jobs.W[6] = p3_Wr; jobs.out[6] = wf_p3r; jobs.K[6] = 256; jobs.Nn[6] = 64;  jobs.nnt[6] = 4;  jobs.nkt[6] = 8;
    jobs.W[7] = pr_W1; jobs.out[7] = wf_pr1; jobs.K[7] = 64;  jobs.Nn[7] = 64;  jobs.nnt[7] = 4;  jobs.nkt[7] = 2;
    wt_frag_all<<<dim3(36, 8), blk, 0, stream>>>(jobs);
    cast_frag<<<dim3(320), blk, 0, stream>>>(xl, N_LOW, 125, xl_f, 320, 4);

    // ===================== combined CSR build ===============================
    hipMemsetAsync(cnt, 0, 2 * (size_t)N * sizeof(int), stream);
    hist_all<<<egrid(ETOT), blk, 0, stream>>>(di_lh, di_hh, cnt);
    scan_partial<<<dim3(NB2), blk, 0, stream>>>(cnt, off, bscan, 2 * N);
    scan_bsums<<<dim3(1), blk, 0, stream>>>(bscan, NB2, off, 2 * N);
    scan_add<<<dim3(NB2), blk, 0, stream>>>(off, bscan, 2 * N);
    hipMemcpyAsync(cur, off, 2 * (size_t)N * sizeof(int), hipMemcpyDeviceToDevice, stream);
    scatter_all<<<egrid(ETOT), blk, 0, stream>>>(si_lh, di_lh, si_hh, di_hh, cur, csr);

    // ===================== d layer (low -> high, H=1, C=256) ================
    hipMemsetAsync(dl_d, 0, (size_t)N_LOW * sizeof(float), stream);
    gemm_dlayer<<<dim3(4, 40), blk, 0, stream>>>(xl_f, wf_d, d_bl, hl, N_LOW, 256, 4, d_att, dl_d);
    gat_gather<1, 256, true><<<wgrid(N), blk, 0, stream>>>(
        hl16, nullptr, xh, d_Wr, d_br, dl_d, nullptr, rp_lh, csr, d_att, d_b,
        xA16, 264, 1, N, zstd);

    // ===================== bn0 + frag cast (stride 264, F=257) =============
    hipMemsetAsync(bsum, 0, 528 * sizeof(float), stream);
    bn_partial3<33, 7><<<dim3(RBLK), blk, 0, stream>>>(xA16, N, partials);
    bn_reduce2<<<dim3(9, 32), blk, 0, stream>>>(partials, 528, bsum);
    bn_frag<false><<<dim3(2048), blk, 0, stream>>>(xA16, N, 257, 264, 264, bsum, bn0_g, bn0_b, AfB, NMT, 9);

    // ===================== p1 (H=4, C=64) ===================================
    gemm_mfma2<<<dim3(4, 391, 2), blk, 0, stream>>>(AfB, wf_p1l, wf_p1r, p1_bl, p1_br, hl, hr, N, 256, 9, p1_att, dl, dr, 4);
    gat_gather<4, 64, false><<<wgrid(N), blk, 0, stream>>>(
        hl16, hr16, nullptr, nullptr, nullptr, dl, dr, rp_hh, csr, p1_att, p1_b,
        xB16, 256, 0, N, nullptr);
    hipMemsetAsync(bsum, 0, 512 * sizeof(float), stream);
    bn_partial3<32, 8><<<dim3(RBLK), blk, 0, stream>>>(xB16, N, partials);
    bn_reduce2<<<dim3(8, 32), blk, 0, stream>>>(partials, 512, bsum);
    bn_frag<true><<<dim3(2048), blk, 0, stream>>>(xB16, N, 256, 256, 256, bsum, bn1_g, bn1_b, AfA, NMT, 8);

    // ===================== p2 (H=4, C=64) ===================================
    gemm_mfma2<<<dim3(4, 391, 2), blk, 0, stream>>>(AfA, wf_p2l, wf_p2r, p2_bl, p2_br, hl, hr, N, 256, 8, p2_att, dl, dr, 4);
    gat_gather<4, 64, false><<<wgrid(N), blk, 0, stream>>>(
        hl16, hr16, nullptr, nullptr, nullptr, dl, dr, rp_hh, csr, p2_att, p2_b,
        xA16, 256, 0, N, nullptr);
    hipMemsetAsync(bsum, 0, 512 * sizeof(float), stream);
    bn_partial3<32, 8><<<dim3(RBLK), blk, 0, stream>>>(xA16, N, partials);
    bn_reduce2<<<dim3(8, 32), blk, 0, stream>>>(partials, 512, bsum);
    bn_frag<true><<<dim3(2048), blk, 0, stream>>>(xA16, N, 256, 256, 256, bsum, bn2_g, bn2_b, AfB, NMT, 8);

    // ===================== p3 (H=1, C=64) ===================================
    gemm_mfma2<<<dim3(1, 391, 2), blk, 0, stream>>>(AfB, wf_p3l, wf_p3r, p3_bl, p3_br, hl, hr, N, 64, 8, p3_att, dl, dr, 1);
    gat_gather<1, 64, false><<<wgrid(N), blk, 0, stream>>>(
        hl16, hr16, nullptr, nullptr, nullptr, dl, dr, rp_hh, csr, p3_att, p3_b,
        xB16, 64, 0, N, nullptr);
    hipMemsetAsync(bsum, 0, 128 * sizeof(float), stream);
    bn_partial3<8, 32><<<dim3(RBLK), blk, 0, stream>>>(xB16, N, partials);
    bn_reduce2<<<dim3(2, 32), blk, 0, stream>>>(partials, 128, bsum);
    bn_frag<true><<<dim3(2048), blk, 0, stream>>>(xB16, N, 64, 64, 64, bsum, bn3_g, bn3_b, AfA, NMT, 2);

    // ===================== predictor MLP ====================================
    gemm_plain<<<dim3(1, 391), blk, 0, stream>>>(AfA, wf_pr1, pr_b1, hl, N, 64, 2);
    dot_w2<<<wgrid(N), blk, 0, stream>>>(hl, pr_W2, pr_b2, y, N);
}

// Round 15
// 543.771 us; speedup vs baseline: 1.0415x; 1.0415x over previous
//
#include <hip/hip_runtime.h>
#include <math.h>

#define DEV __device__ __forceinline__

static const int N_LOW = 5000, N_HIGH = 50000, E_LH = 200000, E_HH = 400000;
static const int E2 = E_HH + N_HIGH;   // 450000 with self loops
static const int ETOT = E_LH + E2;     // 650000 combined
static const int RBLK = 2048;          // bn stage-1 blocks

typedef __attribute__((ext_vector_type(8))) short bf16x8;
typedef __attribute__((ext_vector_type(4))) float f32x4;
typedef __attribute__((ext_vector_type(8))) unsigned short u16x8;
typedef unsigned short u16;

DEV short f2bf(float v) {            // round-to-nearest-even f32 -> bf16
    unsigned u = __float_as_uint(v);
    u += 0x7FFFu + ((u >> 16) & 1u);
    return (short)(u >> 16);
}
DEV float bf2f(u16 u) { return __uint_as_float(((unsigned)u) << 16); }

template <int VPL> struct RawTT { using T = u16; };
template <> struct RawTT<4> { using T = ushort4; };

// =================== MFMA GEMM on fragment-ordered operands =================
template <bool RELU, bool BF16OUT>
DEV void gemm_body(const bf16x8* __restrict__ Af, const bf16x8* __restrict__ Bf,
                   const float* __restrict__ bias, float* __restrict__ C,
                   int M, int N, int nkt) {
    const int l = threadIdx.x & 63;
    const int w = threadIdx.x >> 6;
    const int nt0 = blockIdx.x * 4;
    const int mt0 = blockIdx.y * 8 + w * 2;
    f32x4 acc[2][4];
#pragma unroll
    for (int i = 0; i < 2; i++)
#pragma unroll
        for (int j = 0; j < 4; j++) acc[i][j] = (f32x4){0.f, 0.f, 0.f, 0.f};
    const bf16x8* a0p = Af + (size_t)mt0 * nkt * 64 + l;
    const bf16x8* a1p = a0p + (size_t)nkt * 64;
    const bf16x8* bp = Bf + (size_t)nt0 * nkt * 64 + l;
    for (int kt = 0; kt < nkt; kt++) {
        bf16x8 a0 = a0p[kt * 64];
        bf16x8 a1 = a1p[kt * 64];
        bf16x8 b0 = bp[kt * 64];
        bf16x8 b1 = bp[(size_t)(nkt + kt) * 64];
        bf16x8 b2 = bp[(size_t)(2 * nkt + kt) * 64];
        bf16x8 b3 = bp[(size_t)(3 * nkt + kt) * 64];
        acc[0][0] = __builtin_amdgcn_mfma_f32_16x16x32_bf16(a0, b0, acc[0][0], 0, 0, 0);
        acc[0][1] = __builtin_amdgcn_mfma_f32_16x16x32_bf16(a0, b1, acc[0][1], 0, 0, 0);
        acc[0][2] = __builtin_amdgcn_mfma_f32_16x16x32_bf16(a0, b2, acc[0][2], 0, 0, 0);
        acc[0][3] = __builtin_amdgcn_mfma_f32_16x16x32_bf16(a0, b3, acc[0][3], 0, 0, 0);
        acc[1][0] = __builtin_amdgcn_mfma_f32_16x16x32_bf16(a1, b0, acc[1][0], 0, 0, 0);
        acc[1][1] = __builtin_amdgcn_mfma_f32_16x16x32_bf16(a1, b1, acc[1][1], 0, 0, 0);
        acc[1][2] = __builtin_amdgcn_mfma_f32_16x16x32_bf16(a1, b2, acc[1][2], 0, 0, 0);
        acc[1][3] = __builtin_amdgcn_mfma_f32_16x16x32_bf16(a1, b3, acc[1][3], 0, 0, 0);
    }
    const int colb = nt0 * 16 + (l & 15);
    const int rsub = (l >> 4) * 4;
#pragma unroll
    for (int mi = 0; mi < 2; mi++) {
        int rowb = (mt0 + mi) * 16 + rsub;
#pragma unroll
        for (int r = 0; r < 4; r++) {
            int row = rowb + r;
            if (row >= M) continue;
#pragma unroll
            for (int n = 0; n < 4; n++) {
                int col = colb + n * 16;
                float v = acc[mi][n][r] + bias[col];
                if (RELU) v = fmaxf(v, 0.f);
                if (BF16OUT)
                    ((u16*)C)[(size_t)row * N + col] = (u16)f2bf(v);
                else
                    C[(size_t)row * N + col] = v;
            }
        }
    }
}

template <bool RELU, bool BF16OUT>
__global__ __launch_bounds__(256) void gemm_mfma(
    const bf16x8* __restrict__ Af, const bf16x8* __restrict__ Bf,
    const float* __restrict__ bias, float* __restrict__ C,
    int M, int N, int nkt) {
    gemm_body<RELU, BF16OUT>(Af, Bf, bias, C, M, N, nkt);
}

// paired variant: blockIdx.z selects (Bf0,bias0,C0) or (Bf1,bias1,C1); same A.
__global__ __launch_bounds__(256) void gemm_mfma2(
    const bf16x8* __restrict__ Af,
    const bf16x8* __restrict__ Bf0, const bf16x8* __restrict__ Bf1,
    const float* __restrict__ bias0, const float* __restrict__ bias1,
    float* __restrict__ C0, float* __restrict__ C1,
    int M, int N, int nkt) {
    if (blockIdx.z == 0)
        gemm_body<false, true>(Af, Bf0, bias0, C0, M, N, nkt);
    else
        gemm_body<false, true>(Af, Bf1, bias1, C1, M, N, nkt);
}

// --------- BN-apply (stats from raw sums) + (relu) + bf16 frag cast --------
template <bool RELU>
__global__ __launch_bounds__(256) void bn_frag(
    const u16* __restrict__ x, int Nrows, int F, int STR, int SS,
    const float* __restrict__ sums,
    const float* __restrict__ g, const float* __restrict__ b,
    bf16x8* __restrict__ Af, int nmt, int nkt) {
    int total = nmt * nkt * 64;
    for (int idx = blockIdx.x * blockDim.x + threadIdx.x; idx < total;
         idx += gridDim.x * blockDim.x) {
        int mt = idx / (nkt * 64);
        int rem = idx - mt * (nkt * 64);
        int kt = rem >> 6, l = rem & 63;
        int row = mt * 16 + (l & 15);
        int colb = kt * 32 + (l >> 4) * 8;
        bf16x8 o;
#pragma unroll
        for (int j = 0; j < 8; j++) {
            int col = colb + j;
            float v = 0.f;
            if (row < Nrows && col < F) {
                float mu = sums[col] / Nrows;
                float var = sums[SS + col] / Nrows - mu * mu;
                float istd = rsqrtf(fmaxf(var, 0.f) + 1e-5f);
                v = (bf2f(x[(size_t)row * STR + col]) - mu) * istd * g[col] + b[col];
                if (RELU) v = fmaxf(v, 0.f);
            }
            o[j] = f2bf(v);
        }
        Af[idx] = o;
    }
}

// --------- plain cast (xl f32) into fragment-ordered A, zero-padded --------
__global__ __launch_bounds__(256) void cast_frag(
    const float* __restrict__ x, int Nrows, int F,
    bf16x8* __restrict__ Af, int nmt, int nkt) {
    int total = nmt * nkt * 64;
    for (int idx = blockIdx.x * blockDim.x + threadIdx.x; idx < total;
         idx += gridDim.x * blockDim.x) {
        int mt = idx / (nkt * 64);
        int rem = idx - mt * (nkt * 64);
        int kt = rem >> 6, l = rem & 63;
        int row = mt * 16 + (l & 15);
        int colb = kt * 32 + (l >> 4) * 8;
        bf16x8 o;
#pragma unroll
        for (int j = 0; j < 8; j++) {
            int col = colb + j;
            o[j] = (row < Nrows && col < F) ? f2bf(x[(size_t)row * F + col]) : (short)0;
        }
        Af[idx] = o;
    }
}

// --------- ALL weight [K][N] -> fragment-ordered B transforms in one -------
struct WtJobs {
    const float* W[8];
    bf16x8* out[8];
    int K[8], Nn[8], nnt[8], nkt[8];
};
__global__ __launch_bounds__(256) void wt_frag_all(WtJobs jobs) {
    const int job = blockIdx.y;
    const float* W = jobs.W[job];
    bf16x8* Bf = jobs.out[job];
    const int K = jobs.K[job], N = jobs.Nn[job];
    const int nkt = jobs.nkt[job];
    int total = jobs.nnt[job] * nkt * 64;
    for (int idx = blockIdx.x * blockDim.x + threadIdx.x; idx < total;
         idx += gridDim.x * blockDim.x) {
        int nt = idx / (nkt * 64);
        int rem = idx - nt * (nkt * 64);
        int kt = rem >> 6, l = rem & 63;
        int col = nt * 16 + (l & 15);
        int kb = kt * 32 + (l >> 4) * 8;
        bf16x8 o;
#pragma unroll
        for (int j = 0; j < 8; j++) {
            int k = kb + j;
            o[j] = (k < K && col < N) ? f2bf(W[(size_t)k * N + col]) : (short)0;
        }
        Bf[idx] = o;
    }
}

// ------------- combined CSR build over BOTH edge sets ----------------------
__global__ __launch_bounds__(256) void hist_all(
    const int* __restrict__ di_lh, const int* __restrict__ di_hh,
    int* __restrict__ cnt) {
    for (int i = blockIdx.x * blockDim.x + threadIdx.x; i < ETOT;
         i += gridDim.x * blockDim.x) {
        if (i < E_LH) {
            atomicAdd(&cnt[di_lh[i]], 1);
        } else {
            int j = i - E_LH;
            int d = (j < E_HH) ? di_hh[j] : (j - E_HH);
            atomicAdd(&cnt[N_HIGH + d], 1);
        }
    }
}

// ---- parallel exclusive scan over n ints (3 kernels, chunks of 1024) -------
__global__ __launch_bounds__(256) void scan_partial(
    const int* __restrict__ cnt, int* __restrict__ off,
    int* __restrict__ bsum, int n) {
    __shared__ int s[256];
    const int t = threadIdx.x;
    const int base = blockIdx.x * 1024 + t * 4;
    int v0 = (base < n) ? cnt[base] : 0;
    int v1 = (base + 1 < n) ? cnt[base + 1] : 0;
    int v2 = (base + 2 < n) ? cnt[base + 2] : 0;
    int v3 = (base + 3 < n) ? cnt[base + 3] : 0;
    int tsum = v0 + v1 + v2 + v3;
    s[t] = tsum;
    __syncthreads();
    for (int step = 1; step < 256; step <<= 1) {
        int q = (t >= step) ? s[t - step] : 0;
        __syncthreads();
        s[t] += q;
        __syncthreads();
    }
    int excl = s[t] - tsum;
    if (base < n) off[base] = excl;
    if (base + 1 < n) off[base + 1] = excl + v0;
    if (base + 2 < n) off[base + 2] = excl + v0 + v1;
    if (base + 3 < n) off[base + 3] = excl + v0 + v1 + v2;
    if (t == 255) bsum[blockIdx.x] = s[255];
}

__global__ __launch_bounds__(256) void scan_bsums(
    int* __restrict__ bsum, int nb, int* __restrict__ off, int n) {
    __shared__ int s[256];
    const int t = threadIdx.x;
    int v = (t < nb) ? bsum[t] : 0;
    s[t] = v;
    __syncthreads();
    for (int step = 1; step < 256; step <<= 1) {
        int q = (t >= step) ? s[t - step] : 0;
        __syncthreads();
        s[t] += q;
        __syncthreads();
    }
    if (t < nb) bsum[t] = s[t] - v;          // exclusive
    if (t == 255) off[n] = s[255];           // grand total
}

__global__ __launch_bounds__(256) void scan_add(
    int* __restrict__ off, const int* __restrict__ bsum, int n) {
    int b = blockIdx.x;
    int add = bsum[b];
    int base = b * 1024;
    int end = base + 1024 < n ? base + 1024 : n;
    for (int i = base + threadIdx.x; i < end; i += 256) off[i] += add;
}

__global__ __launch_bounds__(256) void scatter_all(
    const int* __restrict__ si_lh, const int* __restrict__ di_lh,
    const int* __restrict__ si_hh, const int* __restrict__ di_hh,
    int* __restrict__ cur, int* __restrict__ csr) {
    for (int i = blockIdx.x * blockDim.x + threadIdx.x; i < ETOT;
         i += gridDim.x * blockDim.x) {
        int d, s, bucket;
        if (i < E_LH) {
            d = di_lh[i]; s = si_lh[i]; bucket = d;
        } else {
            int j = i - E_LH;
            if (j < E_HH) { d = di_hh[j]; s = si_hh[j]; }
            else { d = s = j - E_HH; }
            bucket = N_HIGH + d;
        }
        int p = atomicAdd(&cur[bucket], 1);
        csr[p] = s;
    }
}

// ---------- fused GATv2 (bf16 hl/hr, bf16 out): defer-max online softmax ---
// Softmax shift-invariance: tracking a stale max m with v <= m+8 is exact;
// p = exp(v-m) <= e^8, degree <= ~100 -> s <= 3e5, fp32-safe.
template <int H, int C, bool HR_ONFLY>
__global__ __launch_bounds__(256) void gat_gather(
    const u16* __restrict__ hl, const u16* __restrict__ hr,
    const float* __restrict__ xh, const float* __restrict__ Wr,
    const float* __restrict__ br,
    const int* __restrict__ rowptr, const int* __restrict__ csr_src,
    const float* __restrict__ att, const float* __restrict__ bias,
    u16* __restrict__ out, int outStride, int outOfs, int Ndst,
    const float* __restrict__ col0) {
    constexpr int HC = H * C;
    constexpr int VPL = HC / 64;
    constexpr int LPH = C / VPL;
    using RawT = typename RawTT<VPL>::T;
    int w = blockIdx.x * (blockDim.x >> 6) + (threadIdx.x >> 6);
    if (w >= Ndst) return;
    const int l = threadIdx.x & 63;

    float hrv[VPL], attv[VPL];
    if constexpr (HR_ONFLY) {
        static_assert(!HR_ONFLY || VPL == 4, "onfly assumes VPL==4");
        float xv = xh[w];
        float4 wr = *reinterpret_cast<const float4*>(Wr + l * 4);
        float4 bb = *reinterpret_cast<const float4*>(br + l * 4);
        hrv[0] = fmaf(xv, wr.x, bb.x); hrv[1] = fmaf(xv, wr.y, bb.y);
        hrv[2] = fmaf(xv, wr.z, bb.z); hrv[3] = fmaf(xv, wr.w, bb.w);
        float4 u = *reinterpret_cast<const float4*>(att + l * 4);
        attv[0] = u.x; attv[1] = u.y; attv[2] = u.z; attv[3] = u.w;
    } else if constexpr (VPL == 4) {
        ushort4 t = *(reinterpret_cast<const ushort4*>(hr + (size_t)w * HC) + l);
        hrv[0] = bf2f(t.x); hrv[1] = bf2f(t.y); hrv[2] = bf2f(t.z); hrv[3] = bf2f(t.w);
        float4 u = *reinterpret_cast<const float4*>(att + l * 4);
        attv[0] = u.x; attv[1] = u.y; attv[2] = u.z; attv[3] = u.w;
    } else {
#pragma unroll
        for (int j = 0; j < VPL; j++) {
            hrv[j] = bf2f(hr[(size_t)w * HC + l * VPL + j]);
            attv[j] = att[l * VPL + j];
        }
    }

    const int e0 = rowptr[w], e1 = rowptr[w + 1];
    float m = -3.4e38f, s = 0.f;
    float acc[VPL] = {};

    auto ldraw = [&](int sv) -> RawT {
        if constexpr (VPL == 4)
            return *(reinterpret_cast<const ushort4*>(hl + (size_t)sv * HC) + l);
        else
            return hl[(size_t)sv * HC + l];
    };
    auto proc = [&](RawT t) {
        float hlv[VPL];
        if constexpr (VPL == 4) {
            hlv[0] = bf2f(t.x); hlv[1] = bf2f(t.y);
            hlv[2] = bf2f(t.z); hlv[3] = bf2f(t.w);
        } else {
            hlv[0] = bf2f(t);
        }
        float v = 0.f;
#pragma unroll
        for (int j = 0; j < VPL; j++) {
            float z = hlv[j] + hrv[j];
            v = fmaf(fmaxf(z, 0.2f * z), attv[j], v);
        }
#pragma unroll
        for (int t2 = 1; t2 < LPH; t2 <<= 1) v += __shfl_xor(v, t2, 64);
        float dd = v - m;
        if (__any(dd > 8.f)) {           // rare: stale max off by > threshold
            bool up = dd > 8.f;
            float arg = up ? -dd : dd;
            float ef = __expf(arg);
            float sc = up ? ef : 1.f;
            float p  = up ? 1.f : ef;
            m = up ? v : m;
            s = fmaf(s, sc, p);
#pragma unroll
            for (int j = 0; j < VPL; j++) acc[j] = fmaf(acc[j], sc, p * hlv[j]);
        } else {                          // common: no rescale
            float p = __expf(dd);
            s += p;
#pragma unroll
            for (int j = 0; j < VPL; j++) acc[j] = fmaf(p, hlv[j], acc[j]);
        }
    };

    int e = e0;
    for (; e + 3 < e1; e += 4) {
        int sv0 = csr_src[e];
        int sv1 = csr_src[e + 1];
        int sv2 = csr_src[e + 2];
        int sv3 = csr_src[e + 3];
        RawT t0 = ldraw(sv0);
        RawT t1 = ldraw(sv1);
        RawT t2 = ldraw(sv2);
        RawT t3 = ldraw(sv3);
        proc(t0); proc(t1); proc(t2); proc(t3);
    }
    for (; e < e1; e++) {
        RawT t = ldraw(csr_src[e]);
        proc(t);
    }

    float inv = 1.f / (s + 1e-16f);
    float dnorm = inv / fmaxf((float)(e1 - e0), 1.f);
    if constexpr (VPL == 4) {
        if (((outOfs | outStride) & 3) == 0) {
            ushort4 o;
            o.x = (u16)f2bf(acc[0] * dnorm + bias[l * 4 + 0]);
            o.y = (u16)f2bf(acc[1] * dnorm + bias[l * 4 + 1]);
            o.z = (u16)f2bf(acc[2] * dnorm + bias[l * 4 + 2]);
            o.w = (u16)f2bf(acc[3] * dnorm + bias[l * 4 + 3]);
            *(reinterpret_cast<ushort4*>(out + (size_t)w * outStride + outOfs) + l) = o;
        } else {
#pragma unroll
            for (int j = 0; j < 4; j++)
                out[(size_t)w * outStride + outOfs + l * 4 + j] =
                    (u16)f2bf(acc[j] * dnorm + bias[l * 4 + j]);
        }
    } else {
#pragma unroll
        for (int j = 0; j < VPL; j++)
            out[(size_t)w * outStride + outOfs + l * VPL + j] =
                (u16)f2bf(acc[j] * dnorm + bias[l * VPL + j]);
    }
    if (col0 && l == 0) out[(size_t)w * outStride] = (u16)f2bf(col0[w]);
}

// ----------- BN stats stage 1: ushort8 loads, LDS reduce, no atomics -------
template <int NC, int RPB>
__global__ __launch_bounds__(256) void bn_partial3(
    const u16* __restrict__ x, int Nrows, float* __restrict__ partials) {
    constexpr int STR = NC * 8;
    constexpr int NSTAT = 2 * NC * 8;
    const int t = threadIdx.x;
    const int b = blockIdx.x;
    __shared__ float l1[NC * RPB * 8];
    __shared__ float l2[NC * RPB * 8];
    float s1[8] = {}, s2[8] = {};
    if (t < NC * RPB) {
        const int rg = t / NC, cg = t - (t / NC) * NC;
        for (int r = b * RPB + rg; r < Nrows; r += RBLK * RPB) {
            u16x8 p = *reinterpret_cast<const u16x8*>(x + (size_t)r * STR + cg * 8);
#pragma unroll
            for (int j = 0; j < 8; j++) {
                float v = bf2f(p[j]);
                s1[j] += v; s2[j] += v * v;
            }
        }
#pragma unroll
        for (int j = 0; j < 8; j++) {
            l1[t * 8 + j] = s1[j];
            l2[t * 8 + j] = s2[j];
        }
    }
    __syncthreads();
    if (t < NC) {
        float a[8] = {}, c[8] = {};
#pragma unroll
        for (int rg = 0; rg < RPB; rg++)
#pragma unroll
            for (int j = 0; j < 8; j++) {
                a[j] += l1[(rg * NC + t) * 8 + j];
                c[j] += l2[(rg * NC + t) * 8 + j];
            }
#pragma unroll
        for (int j = 0; j < 8; j++) {
            partials[(size_t)b * NSTAT + t * 8 + j] = a[j];
            partials[(size_t)b * NSTAT + NC * 8 + t * 8 + j] = c[j];
        }
    }
}

// ----------- BN stats stage 2: 2D grid, coalesced, few atomics -------------
__global__ __launch_bounds__(256) void bn_reduce2(
    const float* __restrict__ partials, int nstat, float* __restrict__ bsum) {
    const int sl = threadIdx.x & 63, ch = threadIdx.x >> 6;
    const int s = blockIdx.x * 64 + sl;
    const int b0 = blockIdx.y * (RBLK / 32);
    float v = 0.f;
    if (s < nstat) {
        for (int b = b0 + ch; b < b0 + RBLK / 32; b += 4)
            v += partials[(size_t)b * nstat + s];
    }
    __shared__ float l[256];
    l[threadIdx.x] = v;
    __syncthreads();
    if (ch == 0 && s < nstat)
        atomicAdd(&bsum[s], l[sl] + l[sl + 64] + l[sl + 128] + l[sl + 192]);
}

// y[i] = dot64(hid[i], W2) + b2
__global__ __launch_bounds__(256) void dot_w2(const float* __restrict__ hid,
                                              const float* __restrict__ W2,
                                              const float* __restrict__ b2,
                                              float* __restrict__ y, int N) {
    int w = blockIdx.x * (blockDim.x >> 6) + (threadIdx.x >> 6);
    int l = threadIdx.x & 63;
    if (w >= N) return;
    float v = hid[(size_t)w * 64 + l] * W2[l];
#pragma unroll
    for (int m = 1; m < 64; m <<= 1) v += __shfl_xor(v, m, 64);
    if (l == 0) y[w] = v + b2[0];
}

// ---------------------------------------------------------------------------
extern "C" void kernel_launch(void* const* d_in, const int* in_sizes, int n_in,
                              void* d_out, int out_size, void* d_ws, size_t ws_size,
                              hipStream_t stream) {
    const float* xl   = (const float*)d_in[0];
    const float* xh   = (const float*)d_in[1];
    const float* zstd = (const float*)d_in[2];
    const int* si_lh  = (const int*)d_in[3];
    const int* di_lh  = (const int*)d_in[4];
    const int* si_hh  = (const int*)d_in[5];
    const int* di_hh  = (const int*)d_in[6];
    int a = 7;
    const float *d_Wl = (const float*)d_in[a++], *d_bl = (const float*)d_in[a++],
                *d_Wr = (const float*)d_in[a++], *d_br = (const float*)d_in[a++],
                *d_att = (const float*)d_in[a++], *d_b = (const float*)d_in[a++];
    const float *p1_Wl = (const float*)d_in[a++], *p1_bl = (const float*)d_in[a++],
                *p1_Wr = (const float*)d_in[a++], *p1_br = (const float*)d_in[a++],
                *p1_att = (const float*)d_in[a++], *p1_b = (const float*)d_in[a++];
    const float *p2_Wl = (const float*)d_in[a++], *p2_bl = (const float*)d_in[a++],
                *p2_Wr = (const float*)d_in[a++], *p2_br = (const float*)d_in[a++],
                *p2_att = (const float*)d_in[a++], *p2_b = (const float*)d_in[a++];
    const float *p3_Wl = (const float*)d_in[a++], *p3_bl = (const float*)d_in[a++],
                *p3_Wr = (const float*)d_in[a++], *p3_br = (const float*)d_in[a++],
                *p3_att = (const float*)d_in[a++], *p3_b = (const float*)d_in[a++];
    const float *bn0_g = (const float*)d_in[a++], *bn0_b = (const float*)d_in[a++],
                *bn1_g = (const float*)d_in[a++], *bn1_b = (const float*)d_in[a++],
                *bn2_g = (const float*)d_in[a++], *bn2_b = (const float*)d_in[a++],
                *bn3_g = (const float*)d_in[a++], *bn3_b = (const float*)d_in[a++];
    const float *pr_W1 = (const float*)d_in[a++], *pr_b1 = (const float*)d_in[a++],
                *pr_W2 = (const float*)d_in[a++], *pr_b2 = (const float*)d_in[a++];
    float* y = (float*)d_out;

    const int N = N_HIGH;
    const int NMT = 3125;                    // 50000/16
    const int NB2 = (2 * N + 1023) / 1024;   // scan blocks over 2N = 98
    // ---- workspace layout ----
    float* ws = (float*)d_ws;
    float* xA = ws;                           // region 50000*257 f32 (bf16 stride-264 used / hosts AfA)
    float* xB = xA + (size_t)N * 257;         // region 50000*256 f32 (bf16 used / hosts AfB)
    float* hl = xB + (size_t)N * 256;         // 50000*256 (bf16 used)
    float* hr = hl + (size_t)N * 256;         // 50000*256 (bf16 used; dead during BN -> partials)
    bf16x8* xl_f = (bf16x8*)(hr + (size_t)N * 256);   // 320*4*64 frags
    bf16x8* wf_d   = xl_f + 320 * 4 * 64;     // 16*4*64
    bf16x8* wf_p1l = wf_d + 16 * 4 * 64;      // 16*9*64
    bf16x8* wf_p1r = wf_p1l + 16 * 9 * 64;
    bf16x8* wf_p2l = wf_p1r + 16 * 9 * 64;    // 16*8*64
    bf16x8* wf_p2r = wf_p2l + 16 * 8 * 64;
    bf16x8* wf_p3l = wf_p2r + 16 * 8 * 64;    // 4*8*64
    bf16x8* wf_p3r = wf_p3l + 4 * 8 * 64;
    bf16x8* wf_pr1 = wf_p3r + 4 * 8 * 64;     // 4*2*64
    float* bsum = (float*)(wf_pr1 + 4 * 2 * 64); // 544
    int* bscan  = (int*)(bsum + 544);         // 256
    int* cnt    = bscan + 256;                // 2N
    int* off    = cnt + 2 * N;                // 2N+1
    int* cur    = off + 2 * N + 1;            // 2N
    int* csr    = cur + 2 * N;                // 650000
    size_t need = (size_t)((char*)(csr + ETOT) - (char*)ws);
    if (ws_size < need) return;
    bf16x8* AfB = (bf16x8*)xB;
    bf16x8* AfA = (bf16x8*)xA;
    u16* xA16 = (u16*)xA;        // stride-264 bf16 rows
    u16* xB16 = (u16*)xB;
    u16* hl16 = (u16*)hl;
    u16* hr16 = (u16*)hr;
    float* partials = hr;        // overlay: hr region dead during BN stats
    int* rp_lh = off;
    int* rp_hh = off + N;

    dim3 blk(256);
    auto wgrid = [](int E) { return dim3((E + 3) / 4); };
    auto egrid = [](size_t total) {
        size_t g = (total + 255) / 256;
        return dim3((unsigned)(g > 2048 ? 2048 : g));
    };

    // ===================== weight fragment transforms (one kernel) ==========
    WtJobs jobs;
    jobs.W[0] = d_Wl;  jobs.out[0] = wf_d;   jobs.K[0] = 125; jobs.Nn[0] = 256; jobs.nnt[0] = 16; jobs.nkt[0] = 4;
    jobs.W[1] = p1_Wl; jobs.out[1] = wf_p1l; jobs.K[1] = 257; jobs.Nn[1] = 256; jobs.nnt[1] = 16; jobs.nkt[1] = 9;
    jobs.W[2] = p1_Wr; jobs.out[2] = wf_p1r; jobs.K[2] = 257; jobs.Nn[2] = 256; jobs.nnt[2] = 16; jobs.nkt[2] = 9;
    jobs.W[3] = p2_Wl; jobs.out[3] = wf_p2l; jobs.K[3] = 256; jobs.Nn[3] = 256; jobs.nnt[3] = 16; jobs.nkt[3] = 8;
    jobs.W[4] = p2_Wr; jobs.out[4] = wf_p2r; jobs.K[4] = 256; jobs.Nn[4] = 256; jobs.nnt[4] = 16; jobs.nkt[4] = 8;
    jobs.W[5] = p3_Wl; jobs.out[5] = wf_p3l; jobs.K[5] = 256; jobs.Nn[5] = 64;  jobs.nnt[5] = 4;  jobs.nkt[5] = 8;
    jobs.W[6] = p3_Wr; jobs.out[6] = wf_p3r; jobs.K[6] = 256; jobs.Nn[6] = 64;  jobs.nnt[6] = 4;  jobs.nkt[6] = 8;
    jobs.W[7] = pr_W1; jobs.out[7] = wf_pr1; jobs.K[7] = 64;  jobs.Nn[7] = 64;  jobs.nnt[7] = 4;  jobs.nkt[7] = 2;
    wt_frag_all<<<dim3(36, 8), blk, 0, stream>>>(jobs);
    cast_frag<<<dim3(320), blk, 0, stream>>>(xl, N_LOW, 125, xl_f, 320, 4);

    // ===================== combined CSR build ===============================
    hipMemsetAsync(cnt, 0, 2 * (size_t)N * sizeof(int), stream);
    hist_all<<<egrid(ETOT), blk, 0, stream>>>(di_lh, di_hh, cnt);
    scan_partial<<<dim3(NB2), blk, 0, stream>>>(cnt, off, bscan, 2 * N);
    scan_bsums<<<dim3(1), blk, 0, stream>>>(bscan, NB2, off, 2 * N);
    scan_add<<<dim3(NB2), blk, 0, stream>>>(off, bscan, 2 * N);
    hipMemcpyAsync(cur, off, 2 * (size_t)N * sizeof(int), hipMemcpyDeviceToDevice, stream);
    scatter_all<<<egrid(ETOT), blk, 0, stream>>>(si_lh, di_lh, si_hh, di_hh, cur, csr);

    // ===================== d layer (low -> high, H=1, C=256) ================
    gemm_mfma<false, true><<<dim3(4, 40), blk, 0, stream>>>(xl_f, wf_d, d_bl, hl, N_LOW, 256, 4);
    gat_gather<1, 256, true><<<wgrid(N), blk, 0, stream>>>(
        hl16, nullptr, xh, d_Wr, d_br, rp_lh, csr, d_att, d_b, xA16, 264, 1, N, zstd);

    // ===================== bn0 + frag cast (stride 264, F=257) =============
    hipMemsetAsync(bsum, 0, 528 * sizeof(float), stream);
    bn_partial3<33, 7><<<dim3(RBLK), blk, 0, stream>>>(xA16, N, partials);
    bn_reduce2<<<dim3(9, 32), blk, 0, stream>>>(partials, 528, bsum);
    bn_frag<false><<<dim3(2048), blk, 0, stream>>>(xA16, N, 257, 264, 264, bsum, bn0_g, bn0_b, AfB, NMT, 9);

    // ===================== p1 (H=4, C=64) ===================================
    gemm_mfma2<<<dim3(4, 391, 2), blk, 0, stream>>>(AfB, wf_p1l, wf_p1r, p1_bl, p1_br, hl, hr, N, 256, 9);
    gat_gather<4, 64, false><<<wgrid(N), blk, 0, stream>>>(
        hl16, hr16, nullptr, nullptr, nullptr, rp_hh, csr, p1_att, p1_b, xB16, 256, 0, N, nullptr);
    hipMemsetAsync(bsum, 0, 512 * sizeof(float), stream);
    bn_partial3<32, 8><<<dim3(RBLK), blk, 0, stream>>>(xB16, N, partials);
    bn_reduce2<<<dim3(8, 32), blk, 0, stream>>>(partials, 512, bsum);
    bn_frag<true><<<dim3(2048), blk, 0, stream>>>(xB16, N, 256, 256, 256, bsum, bn1_g, bn1_b, AfA, NMT, 8);

    // ===================== p2 (H=4, C=64) ===================================
    gemm_mfma2<<<dim3(4, 391, 2), blk, 0, stream>>>(AfA, wf_p2l, wf_p2r, p2_bl, p2_br, hl, hr, N, 256, 8);
    gat_gather<4, 64, false><<<wgrid(N), blk, 0, stream>>>(
        hl16, hr16, nullptr, nullptr, nullptr, rp_hh, csr, p2_att, p2_b, xA16, 256, 0, N, nullptr);
    hipMemsetAsync(bsum, 0, 512 * sizeof(float), stream);
    bn_partial3<32, 8><<<dim3(RBLK), blk, 0, stream>>>(xA16, N, partials);
    bn_reduce2<<<dim3(8, 32), blk, 0, stream>>>(partials, 512, bsum);
    bn_frag<true><<<dim3(2048), blk, 0, stream>>>(xA16, N, 256, 256, 256, bsum, bn2_g, bn2_b, AfB, NMT, 8);

    // ===================== p3 (H=1, C=64) ===================================
    gemm_mfma2<<<dim3(1, 391, 2), blk, 0, stream>>>(AfB, wf_p3l, wf_p3r, p3_bl, p3_br, hl, hr, N, 64, 8);
    gat_gather<1, 64, false><<<wgrid(N), blk, 0, stream>>>(
        hl16, hr16, nullptr, nullptr, nullptr, rp_hh, csr, p3_att, p3_b, xB16, 64, 0, N, nullptr);
    hipMemsetAsync(bsum, 0, 128 * sizeof(float), stream);
    bn_partial3<8, 32><<<dim3(RBLK), blk, 0, stream>>>(xB16, N, partials);
    bn_reduce2<<<dim3(2, 32), blk, 0, stream>>>(partials, 128, bsum);
    bn_frag<true><<<dim3(2048), blk, 0, stream>>>(xB16, N, 64, 64, 64, bsum, bn3_g, bn3_b, AfA, NMT, 2);

    // ===================== predictor MLP ====================================
    gemm_mfma<true, false><<<dim3(1, 391), blk, 0, stream>>>(AfA, wf_pr1, pr_b1, hl, N, 64, 2);
    dot_w2<<<wgrid(N), blk, 0, stream>>>(hl, pr_W2, pr_b2, y, N);
}

// Round 16
// 514.644 us; speedup vs baseline: 1.1004x; 1.0566x over previous
//
#include <hip/hip_runtime.h>
#include <math.h>

#define DEV __device__ __forceinline__

static const int N_LOW = 5000, N_HIGH = 50000, E_LH = 200000, E_HH = 400000;
static const int E2 = E_HH + N_HIGH;   // 450000 with self loops
static const int ETOT = E_LH + E2;     // 650000 combined
static const int RBLK = 2048;          // bn stage-1 blocks

typedef __attribute__((ext_vector_type(8))) short bf16x8;
typedef __attribute__((ext_vector_type(4))) float f32x4;
typedef __attribute__((ext_vector_type(8))) unsigned short u16x8;
typedef unsigned short u16;

DEV short f2bf(float v) {            // round-to-nearest-even f32 -> bf16
    unsigned u = __float_as_uint(v);
    u += 0x7FFFu + ((u >> 16) & 1u);
    return (short)(u >> 16);
}
DEV float bf2f(u16 u) { return __uint_as_float(((unsigned)u) << 16); }

template <int VPL> struct RawTT { using T = u16; };
template <> struct RawTT<4> { using T = ushort4; };

// =================== MFMA GEMM on fragment-ordered operands =================
// WIDE: one block covers ALL 16 nt tiles (256 cols); wave w owns nt w*4..w*4+3
//       and all waves share the same 2 mt row tiles (A-frags L1-broadcast).
//       Removes the 4x A-refetch of the narrow layout. grid (1, M/32, z).
// narrow: block = 4 waves x (2mt x 4nt), grid (N/64, M/128, z).
template <bool RELU, bool BF16OUT, bool WIDE>
DEV void gemm_body(const bf16x8* __restrict__ Af, const bf16x8* __restrict__ Bf,
                   const float* __restrict__ bias, float* __restrict__ C,
                   int M, int N, int nkt) {
    const int l = threadIdx.x & 63;
    const int w = threadIdx.x >> 6;
    const int nt0 = WIDE ? w * 4 : blockIdx.x * 4;
    const int mt0 = WIDE ? blockIdx.y * 2 : blockIdx.y * 8 + w * 2;
    f32x4 acc[2][4];
#pragma unroll
    for (int i = 0; i < 2; i++)
#pragma unroll
        for (int j = 0; j < 4; j++) acc[i][j] = (f32x4){0.f, 0.f, 0.f, 0.f};
    const bf16x8* a0p = Af + (size_t)mt0 * nkt * 64 + l;
    const bf16x8* a1p = a0p + (size_t)nkt * 64;
    const bf16x8* bp = Bf + (size_t)nt0 * nkt * 64 + l;
    for (int kt = 0; kt < nkt; kt++) {
        bf16x8 a0 = a0p[kt * 64];
        bf16x8 a1 = a1p[kt * 64];
        bf16x8 b0 = bp[kt * 64];
        bf16x8 b1 = bp[(size_t)(nkt + kt) * 64];
        bf16x8 b2 = bp[(size_t)(2 * nkt + kt) * 64];
        bf16x8 b3 = bp[(size_t)(3 * nkt + kt) * 64];
        acc[0][0] = __builtin_amdgcn_mfma_f32_16x16x32_bf16(a0, b0, acc[0][0], 0, 0, 0);
        acc[0][1] = __builtin_amdgcn_mfma_f32_16x16x32_bf16(a0, b1, acc[0][1], 0, 0, 0);
        acc[0][2] = __builtin_amdgcn_mfma_f32_16x16x32_bf16(a0, b2, acc[0][2], 0, 0, 0);
        acc[0][3] = __builtin_amdgcn_mfma_f32_16x16x32_bf16(a0, b3, acc[0][3], 0, 0, 0);
        acc[1][0] = __builtin_amdgcn_mfma_f32_16x16x32_bf16(a1, b0, acc[1][0], 0, 0, 0);
        acc[1][1] = __builtin_amdgcn_mfma_f32_16x16x32_bf16(a1, b1, acc[1][1], 0, 0, 0);
        acc[1][2] = __builtin_amdgcn_mfma_f32_16x16x32_bf16(a1, b2, acc[1][2], 0, 0, 0);
        acc[1][3] = __builtin_amdgcn_mfma_f32_16x16x32_bf16(a1, b3, acc[1][3], 0, 0, 0);
    }
    const int colb = nt0 * 16 + (l & 15);
    const int rsub = (l >> 4) * 4;
#pragma unroll
    for (int mi = 0; mi < 2; mi++) {
        int rowb = (mt0 + mi) * 16 + rsub;
#pragma unroll
        for (int r = 0; r < 4; r++) {
            int row = rowb + r;
            if (row >= M) continue;
#pragma unroll
            for (int n = 0; n < 4; n++) {
                int col = colb + n * 16;
                float v = acc[mi][n][r] + bias[col];
                if (RELU) v = fmaxf(v, 0.f);
                if (BF16OUT)
                    ((u16*)C)[(size_t)row * N + col] = (u16)f2bf(v);
                else
                    C[(size_t)row * N + col] = v;
            }
        }
    }
}

template <bool RELU, bool BF16OUT, bool WIDE>
__global__ __launch_bounds__(256) void gemm_mfma(
    const bf16x8* __restrict__ Af, const bf16x8* __restrict__ Bf,
    const float* __restrict__ bias, float* __restrict__ C,
    int M, int N, int nkt) {
    gemm_body<RELU, BF16OUT, WIDE>(Af, Bf, bias, C, M, N, nkt);
}

// paired variant: blockIdx.z selects (Bf0,bias0,C0) or (Bf1,bias1,C1); same A.
template <bool WIDE>
__global__ __launch_bounds__(256) void gemm_mfma2(
    const bf16x8* __restrict__ Af,
    const bf16x8* __restrict__ Bf0, const bf16x8* __restrict__ Bf1,
    const float* __restrict__ bias0, const float* __restrict__ bias1,
    float* __restrict__ C0, float* __restrict__ C1,
    int M, int N, int nkt) {
    if (blockIdx.z == 0)
        gemm_body<false, true, WIDE>(Af, Bf0, bias0, C0, M, N, nkt);
    else
        gemm_body<false, true, WIDE>(Af, Bf1, bias1, C1, M, N, nkt);
}

// --------- BN-apply (stats from raw sums) + (relu) + bf16 frag cast --------
template <bool RELU>
__global__ __launch_bounds__(256) void bn_frag(
    const u16* __restrict__ x, int Nrows, int F, int STR, int SS,
    const float* __restrict__ sums,
    const float* __restrict__ g, const float* __restrict__ b,
    bf16x8* __restrict__ Af, int nmt, int nkt) {
    int total = nmt * nkt * 64;
    for (int idx = blockIdx.x * blockDim.x + threadIdx.x; idx < total;
         idx += gridDim.x * blockDim.x) {
        int mt = idx / (nkt * 64);
        int rem = idx - mt * (nkt * 64);
        int kt = rem >> 6, l = rem & 63;
        int row = mt * 16 + (l & 15);
        int colb = kt * 32 + (l >> 4) * 8;
        bf16x8 o;
#pragma unroll
        for (int j = 0; j < 8; j++) {
            int col = colb + j;
            float v = 0.f;
            if (row < Nrows && col < F) {
                float mu = sums[col] / Nrows;
                float var = sums[SS + col] / Nrows - mu * mu;
                float istd = rsqrtf(fmaxf(var, 0.f) + 1e-5f);
                v = (bf2f(x[(size_t)row * STR + col]) - mu) * istd * g[col] + b[col];
                if (RELU) v = fmaxf(v, 0.f);
            }
            o[j] = f2bf(v);
        }
        Af[idx] = o;
    }
}

// --------- plain cast (xl f32) into fragment-ordered A, zero-padded --------
__global__ __launch_bounds__(256) void cast_frag(
    const float* __restrict__ x, int Nrows, int F,
    bf16x8* __restrict__ Af, int nmt, int nkt) {
    int total = nmt * nkt * 64;
    for (int idx = blockIdx.x * blockDim.x + threadIdx.x; idx < total;
         idx += gridDim.x * blockDim.x) {
        int mt = idx / (nkt * 64);
        int rem = idx - mt * (nkt * 64);
        int kt = rem >> 6, l = rem & 63;
        int row = mt * 16 + (l & 15);
        int colb = kt * 32 + (l >> 4) * 8;
        bf16x8 o;
#pragma unroll
        for (int j = 0; j < 8; j++) {
            int col = colb + j;
            o[j] = (row < Nrows && col < F) ? f2bf(x[(size_t)row * F + col]) : (short)0;
        }
        Af[idx] = o;
    }
}

// --------- ALL weight [K][N] -> fragment-ordered B transforms in one -------
struct WtJobs {
    const float* W[8];
    bf16x8* out[8];
    int K[8], Nn[8], nnt[8], nkt[8];
};
__global__ __launch_bounds__(256) void wt_frag_all(WtJobs jobs) {
    const int job = blockIdx.y;
    const float* W = jobs.W[job];
    bf16x8* Bf = jobs.out[job];
    const int K = jobs.K[job], N = jobs.Nn[job];
    const int nkt = jobs.nkt[job];
    int total = jobs.nnt[job] * nkt * 64;
    for (int idx = blockIdx.x * blockDim.x + threadIdx.x; idx < total;
         idx += gridDim.x * blockDim.x) {
        int nt = idx / (nkt * 64);
        int rem = idx - nt * (nkt * 64);
        int kt = rem >> 6, l = rem & 63;
        int col = nt * 16 + (l & 15);
        int kb = kt * 32 + (l >> 4) * 8;
        bf16x8 o;
#pragma unroll
        for (int j = 0; j < 8; j++) {
            int k = kb + j;
            o[j] = (k < K && col < N) ? f2bf(W[(size_t)k * N + col]) : (short)0;
        }
        Bf[idx] = o;
    }
}

// ------------- combined CSR build over BOTH edge sets ----------------------
__global__ __launch_bounds__(256) void hist_all(
    const int* __restrict__ di_lh, const int* __restrict__ di_hh,
    int* __restrict__ cnt) {
    for (int i = blockIdx.x * blockDim.x + threadIdx.x; i < ETOT;
         i += gridDim.x * blockDim.x) {
        if (i < E_LH) {
            atomicAdd(&cnt[di_lh[i]], 1);
        } else {
            int j = i - E_LH;
            int d = (j < E_HH) ? di_hh[j] : (j - E_HH);
            atomicAdd(&cnt[N_HIGH + d], 1);
        }
    }
}

// ---- parallel exclusive scan over n ints (3 kernels, chunks of 1024) -------
__global__ __launch_bounds__(256) void scan_partial(
    const int* __restrict__ cnt, int* __restrict__ off,
    int* __restrict__ bsum, int n) {
    __shared__ int s[256];
    const int t = threadIdx.x;
    const int base = blockIdx.x * 1024 + t * 4;
    int v0 = (base < n) ? cnt[base] : 0;
    int v1 = (base + 1 < n) ? cnt[base + 1] : 0;
    int v2 = (base + 2 < n) ? cnt[base + 2] : 0;
    int v3 = (base + 3 < n) ? cnt[base + 3] : 0;
    int tsum = v0 + v1 + v2 + v3;
    s[t] = tsum;
    __syncthreads();
    for (int step = 1; step < 256; step <<= 1) {
        int q = (t >= step) ? s[t - step] : 0;
        __syncthreads();
        s[t] += q;
        __syncthreads();
    }
    int excl = s[t] - tsum;
    if (base < n) off[base] = excl;
    if (base + 1 < n) off[base + 1] = excl + v0;
    if (base + 2 < n) off[base + 2] = excl + v0 + v1;
    if (base + 3 < n) off[base + 3] = excl + v0 + v1 + v2;
    if (t == 255) bsum[blockIdx.x] = s[255];
}

__global__ __launch_bounds__(256) void scan_bsums(
    int* __restrict__ bsum, int nb, int* __restrict__ off, int n) {
    __shared__ int s[256];
    const int t = threadIdx.x;
    int v = (t < nb) ? bsum[t] : 0;
    s[t] = v;
    __syncthreads();
    for (int step = 1; step < 256; step <<= 1) {
        int q = (t >= step) ? s[t - step] : 0;
        __syncthreads();
        s[t] += q;
        __syncthreads();
    }
    if (t < nb) bsum[t] = s[t] - v;          // exclusive
    if (t == 255) off[n] = s[255];           // grand total
}

__global__ __launch_bounds__(256) void scan_add(
    int* __restrict__ off, const int* __restrict__ bsum, int n) {
    int b = blockIdx.x;
    int add = bsum[b];
    int base = b * 1024;
    int end = base + 1024 < n ? base + 1024 : n;
    for (int i = base + threadIdx.x; i < end; i += 256) off[i] += add;
}

__global__ __launch_bounds__(256) void scatter_all(
    const int* __restrict__ si_lh, const int* __restrict__ di_lh,
    const int* __restrict__ si_hh, const int* __restrict__ di_hh,
    int* __restrict__ cur, int* __restrict__ csr) {
    for (int i = blockIdx.x * blockDim.x + threadIdx.x; i < ETOT;
         i += gridDim.x * blockDim.x) {
        int d, s, bucket;
        if (i < E_LH) {
            d = di_lh[i]; s = si_lh[i]; bucket = d;
        } else {
            int j = i - E_LH;
            if (j < E_HH) { d = di_hh[j]; s = si_hh[j]; }
            else { d = s = j - E_HH; }
            bucket = N_HIGH + d;
        }
        int p = atomicAdd(&cur[bucket], 1);
        csr[p] = s;
    }
}

// ---------- fused GATv2 (bf16 hl/hr, bf16 out): logit+softmax+mean+bias ----
// (R13 version: branchless single-exp online softmax.)
template <int H, int C, bool HR_ONFLY>
__global__ __launch_bounds__(256) void gat_gather(
    const u16* __restrict__ hl, const u16* __restrict__ hr,
    const float* __restrict__ xh, const float* __restrict__ Wr,
    const float* __restrict__ br,
    const int* __restrict__ rowptr, const int* __restrict__ csr_src,
    const float* __restrict__ att, const float* __restrict__ bias,
    u16* __restrict__ out, int outStride, int outOfs, int Ndst,
    const float* __restrict__ col0) {
    constexpr int HC = H * C;
    constexpr int VPL = HC / 64;
    constexpr int LPH = C / VPL;
    using RawT = typename RawTT<VPL>::T;
    int w = blockIdx.x * (blockDim.x >> 6) + (threadIdx.x >> 6);
    if (w >= Ndst) return;
    const int l = threadIdx.x & 63;

    float hrv[VPL], attv[VPL];
    if constexpr (HR_ONFLY) {
        static_assert(!HR_ONFLY || VPL == 4, "onfly assumes VPL==4");
        float xv = xh[w];
        float4 wr = *reinterpret_cast<const float4*>(Wr + l * 4);
        float4 bb = *reinterpret_cast<const float4*>(br + l * 4);
        hrv[0] = fmaf(xv, wr.x, bb.x); hrv[1] = fmaf(xv, wr.y, bb.y);
        hrv[2] = fmaf(xv, wr.z, bb.z); hrv[3] = fmaf(xv, wr.w, bb.w);
        float4 u = *reinterpret_cast<const float4*>(att + l * 4);
        attv[0] = u.x; attv[1] = u.y; attv[2] = u.z; attv[3] = u.w;
    } else if constexpr (VPL == 4) {
        ushort4 t = *(reinterpret_cast<const ushort4*>(hr + (size_t)w * HC) + l);
        hrv[0] = bf2f(t.x); hrv[1] = bf2f(t.y); hrv[2] = bf2f(t.z); hrv[3] = bf2f(t.w);
        float4 u = *reinterpret_cast<const float4*>(att + l * 4);
        attv[0] = u.x; attv[1] = u.y; attv[2] = u.z; attv[3] = u.w;
    } else {
#pragma unroll
        for (int j = 0; j < VPL; j++) {
            hrv[j] = bf2f(hr[(size_t)w * HC + l * VPL + j]);
            attv[j] = att[l * VPL + j];
        }
    }

    const int e0 = rowptr[w], e1 = rowptr[w + 1];
    float m = -3.4e38f, s = 0.f;
    float acc[VPL] = {};

    auto ldraw = [&](int sv) -> RawT {
        if constexpr (VPL == 4)
            return *(reinterpret_cast<const ushort4*>(hl + (size_t)sv * HC) + l);
        else
            return hl[(size_t)sv * HC + l];
    };
    auto proc = [&](RawT t) {
        float hlv[VPL];
        if constexpr (VPL == 4) {
            hlv[0] = bf2f(t.x); hlv[1] = bf2f(t.y);
            hlv[2] = bf2f(t.z); hlv[3] = bf2f(t.w);
        } else {
            hlv[0] = bf2f(t);
        }
        float v = 0.f;
#pragma unroll
        for (int j = 0; j < VPL; j++) {
            float z = hlv[j] + hrv[j];
            v = fmaf(fmaxf(z, 0.2f * z), attv[j], v);
        }
#pragma unroll
        for (int t2 = 1; t2 < LPH; t2 <<= 1) v += __shfl_xor(v, t2, 64);
        float d = v - m;
        bool up = d > 0.f;
        float ef = __expf(-fabsf(d));   // first edge: d=inf -> ef=0
        float sc = up ? ef : 1.f;
        float p  = up ? 1.f : ef;
        m = up ? v : m;
        s = fmaf(s, sc, p);
#pragma unroll
        for (int j = 0; j < VPL; j++) acc[j] = fmaf(acc[j], sc, p * hlv[j]);
    };

    int e = e0;
    for (; e + 3 < e1; e += 4) {
        int sv0 = csr_src[e];
        int sv1 = csr_src[e + 1];
        int sv2 = csr_src[e + 2];
        int sv3 = csr_src[e + 3];
        RawT t0 = ldraw(sv0);
        RawT t1 = ldraw(sv1);
        RawT t2 = ldraw(sv2);
        RawT t3 = ldraw(sv3);
        proc(t0); proc(t1); proc(t2); proc(t3);
    }
    for (; e < e1; e++) {
        RawT t = ldraw(csr_src[e]);
        proc(t);
    }

    float inv = 1.f / (s + 1e-16f);
    float dnorm = inv / fmaxf((float)(e1 - e0), 1.f);
    if constexpr (VPL == 4) {
        if (((outOfs | outStride) & 3) == 0) {
            ushort4 o;
            o.x = (u16)f2bf(acc[0] * dnorm + bias[l * 4 + 0]);
            o.y = (u16)f2bf(acc[1] * dnorm + bias[l * 4 + 1]);
            o.z = (u16)f2bf(acc[2] * dnorm + bias[l * 4 + 2]);
            o.w = (u16)f2bf(acc[3] * dnorm + bias[l * 4 + 3]);
            *(reinterpret_cast<ushort4*>(out + (size_t)w * outStride + outOfs) + l) = o;
        } else {
#pragma unroll
            for (int j = 0; j < 4; j++)
                out[(size_t)w * outStride + outOfs + l * 4 + j] =
                    (u16)f2bf(acc[j] * dnorm + bias[l * 4 + j]);
        }
    } else {
#pragma unroll
        for (int j = 0; j < VPL; j++)
            out[(size_t)w * outStride + outOfs + l * VPL + j] =
                (u16)f2bf(acc[j] * dnorm + bias[l * VPL + j]);
    }
    if (col0 && l == 0) out[(size_t)w * outStride] = (u16)f2bf(col0[w]);
}

// ----------- BN stats stage 1: ushort8 loads, LDS reduce, no atomics -------
template <int NC, int RPB>
__global__ __launch_bounds__(256) void bn_partial3(
    const u16* __restrict__ x, int Nrows, float* __restrict__ partials) {
    constexpr int STR = NC * 8;
    constexpr int NSTAT = 2 * NC * 8;
    const int t = threadIdx.x;
    const int b = blockIdx.x;
    __shared__ float l1[NC * RPB * 8];
    __shared__ float l2[NC * RPB * 8];
    float s1[8] = {}, s2[8] = {};
    if (t < NC * RPB) {
        const int rg = t / NC, cg = t - (t / NC) * NC;
        for (int r = b * RPB + rg; r < Nrows; r += RBLK * RPB) {
            u16x8 p = *reinterpret_cast<const u16x8*>(x + (size_t)r * STR + cg * 8);
#pragma unroll
            for (int j = 0; j < 8; j++) {
                float v = bf2f(p[j]);
                s1[j] += v; s2[j] += v * v;
            }
        }
#pragma unroll
        for (int j = 0; j < 8; j++) {
            l1[t * 8 + j] = s1[j];
            l2[t * 8 + j] = s2[j];
        }
    }
    __syncthreads();
    if (t < NC) {
        float a[8] = {}, c[8] = {};
#pragma unroll
        for (int rg = 0; rg < RPB; rg++)
#pragma unroll
            for (int j = 0; j < 8; j++) {
                a[j] += l1[(rg * NC + t) * 8 + j];
                c[j] += l2[(rg * NC + t) * 8 + j];
            }
#pragma unroll
        for (int j = 0; j < 8; j++) {
            partials[(size_t)b * NSTAT + t * 8 + j] = a[j];
            partials[(size_t)b * NSTAT + NC * 8 + t * 8 + j] = c[j];
        }
    }
}

// ----------- BN stats stage 2: 2D grid, coalesced, few atomics -------------
__global__ __launch_bounds__(256) void bn_reduce2(
    const float* __restrict__ partials, int nstat, float* __restrict__ bsum) {
    const int sl = threadIdx.x & 63, ch = threadIdx.x >> 6;
    const int s = blockIdx.x * 64 + sl;
    const int b0 = blockIdx.y * (RBLK / 32);
    float v = 0.f;
    if (s < nstat) {
        for (int b = b0 + ch; b < b0 + RBLK / 32; b += 4)
            v += partials[(size_t)b * nstat + s];
    }
    __shared__ float l[256];
    l[threadIdx.x] = v;
    __syncthreads();
    if (ch == 0 && s < nstat)
        atomicAdd(&bsum[s], l[sl] + l[sl + 64] + l[sl + 128] + l[sl + 192]);
}

// y[i] = dot64(hid[i], W2) + b2
__global__ __launch_bounds__(256) void dot_w2(const float* __restrict__ hid,
                                              const float* __restrict__ W2,
                                              const float* __restrict__ b2,
                                              float* __restrict__ y, int N) {
    int w = blockIdx.x * (blockDim.x >> 6) + (threadIdx.x >> 6);
    int l = threadIdx.x & 63;
    if (w >= N) return;
    float v = hid[(size_t)w * 64 + l] * W2[l];
#pragma unroll
    for (int m = 1; m < 64; m <<= 1) v += __shfl_xor(v, m, 64);
    if (l == 0) y[w] = v + b2[0];
}

// ---------------------------------------------------------------------------
extern "C" void kernel_launch(void* const* d_in, const int* in_sizes, int n_in,
                              void* d_out, int out_size, void* d_ws, size_t ws_size,
                              hipStream_t stream) {
    const float* xl   = (const float*)d_in[0];
    const float* xh   = (const float*)d_in[1];
    const float* zstd = (const float*)d_in[2];
    const int* si_lh  = (const int*)d_in[3];
    const int* di_lh  = (const int*)d_in[4];
    const int* si_hh  = (const int*)d_in[5];
    const int* di_hh  = (const int*)d_in[6];
    int a = 7;
    const float *d_Wl = (const float*)d_in[a++], *d_bl = (const float*)d_in[a++],
                *d_Wr = (const float*)d_in[a++], *d_br = (const float*)d_in[a++],
                *d_att = (const float*)d_in[a++], *d_b = (const float*)d_in[a++];
    const float *p1_Wl = (const float*)d_in[a++], *p1_bl = (const float*)d_in[a++],
                *p1_Wr = (const float*)d_in[a++], *p1_br = (const float*)d_in[a++],
                *p1_att = (const float*)d_in[a++], *p1_b = (const float*)d_in[a++];
    const float *p2_Wl = (const float*)d_in[a++], *p2_bl = (const float*)d_in[a++],
                *p2_Wr = (const float*)d_in[a++], *p2_br = (const float*)d_in[a++],
                *p2_att = (const float*)d_in[a++], *p2_b = (const float*)d_in[a++];
    const float *p3_Wl = (const float*)d_in[a++], *p3_bl = (const float*)d_in[a++],
                *p3_Wr = (const float*)d_in[a++], *p3_br = (const float*)d_in[a++],
                *p3_att = (const float*)d_in[a++], *p3_b = (const float*)d_in[a++];
    const float *bn0_g = (const float*)d_in[a++], *bn0_b = (const float*)d_in[a++],
                *bn1_g = (const float*)d_in[a++], *bn1_b = (const float*)d_in[a++],
                *bn2_g = (const float*)d_in[a++], *bn2_b = (const float*)d_in[a++],
                *bn3_g = (const float*)d_in[a++], *bn3_b = (const float*)d_in[a++];
    const float *pr_W1 = (const float*)d_in[a++], *pr_b1 = (const float*)d_in[a++],
                *pr_W2 = (const float*)d_in[a++], *pr_b2 = (const float*)d_in[a++];
    float* y = (float*)d_out;

    const int N = N_HIGH;
    const int NMT = 3125;                    // 50000/16
    const int NB2 = (2 * N + 1023) / 1024;   // scan blocks over 2N = 98
    // ---- workspace layout ----
    float* ws = (float*)d_ws;
    float* xA = ws;                           // region 50000*257 f32 (bf16 stride-264 used / hosts AfA)
    float* xB = xA + (size_t)N * 257;         // region 50000*256 f32 (bf16 used / hosts AfB)
    float* hl = xB + (size_t)N * 256;         // 50000*256 (bf16 used)
    float* hr = hl + (size_t)N * 256;         // 50000*256 (bf16 used; dead during BN -> partials)
    bf16x8* xl_f = (bf16x8*)(hr + (size_t)N * 256);   // 320*4*64 frags
    bf16x8* wf_d   = xl_f + 320 * 4 * 64;     // 16*4*64
    bf16x8* wf_p1l = wf_d + 16 * 4 * 64;      // 16*9*64
    bf16x8* wf_p1r = wf_p1l + 16 * 9 * 64;
    bf16x8* wf_p2l = wf_p1r + 16 * 9 * 64;    // 16*8*64
    bf16x8* wf_p2r = wf_p2l + 16 * 8 * 64;
    bf16x8* wf_p3l = wf_p2r + 16 * 8 * 64;    // 4*8*64
    bf16x8* wf_p3r = wf_p3l + 4 * 8 * 64;
    bf16x8* wf_pr1 = wf_p3r + 4 * 8 * 64;     // 4*2*64
    float* bsum = (float*)(wf_pr1 + 4 * 2 * 64); // 544
    int* bscan  = (int*)(bsum + 544);         // 256
    int* cnt    = bscan + 256;                // 2N
    int* off    = cnt + 2 * N;                // 2N+1
    int* cur    = off + 2 * N + 1;            // 2N
    int* csr    = cur + 2 * N;                // 650000
    size_t need = (size_t)((char*)(csr + ETOT) - (char*)ws);
    if (ws_size < need) return;
    bf16x8* AfB = (bf16x8*)xB;
    bf16x8* AfA = (bf16x8*)xA;
    u16* xA16 = (u16*)xA;        // stride-264 bf16 rows
    u16* xB16 = (u16*)xB;
    u16* hl16 = (u16*)hl;
    u16* hr16 = (u16*)hr;
    float* partials = hr;        // overlay: hr region dead during BN stats
    int* rp_lh = off;
    int* rp_hh = off + N;

    dim3 blk(256);
    auto wgrid = [](int E) { return dim3((E + 3) / 4); };
    auto egrid = [](size_t total) {
        size_t g = (total + 255) / 256;
        return dim3((unsigned)(g > 2048 ? 2048 : g));
    };

    // ===================== weight fragment transforms (one kernel) ==========
    WtJobs jobs;
    jobs.W[0] = d_Wl;  jobs.out[0] = wf_d;   jobs.K[0] = 125; jobs.Nn[0] = 256; jobs.nnt[0] = 16; jobs.nkt[0] = 4;
    jobs.W[1] = p1_Wl; jobs.out[1] = wf_p1l; jobs.K[1] = 257; jobs.Nn[1] = 256; jobs.nnt[1] = 16; jobs.nkt[1] = 9;
    jobs.W[2] = p1_Wr; jobs.out[2] = wf_p1r; jobs.K[2] = 257; jobs.Nn[2] = 256; jobs.nnt[2] = 16; jobs.nkt[2] = 9;
    jobs.W[3] = p2_Wl; jobs.out[3] = wf_p2l; jobs.K[3] = 256; jobs.Nn[3] = 256; jobs.nnt[3] = 16; jobs.nkt[3] = 8;
    jobs.W[4] = p2_Wr; jobs.out[4] = wf_p2r; jobs.K[4] = 256; jobs.Nn[4] = 256; jobs.nnt[4] = 16; jobs.nkt[4] = 8;
    jobs.W[5] = p3_Wl; jobs.out[5] = wf_p3l; jobs.K[5] = 256; jobs.Nn[5] = 64;  jobs.nnt[5] = 4;  jobs.nkt[5] = 8;
    jobs.W[6] = p3_Wr; jobs.out[6] = wf_p3r; jobs.K[6] = 256; jobs.Nn[6] = 64;  jobs.nnt[6] = 4;  jobs.nkt[6] = 8;
    jobs.W[7] = pr_W1; jobs.out[7] = wf_pr1; jobs.K[7] = 64;  jobs.Nn[7] = 64;  jobs.nnt[7] = 4;  jobs.nkt[7] = 2;
    wt_frag_all<<<dim3(36, 8), blk, 0, stream>>>(jobs);
    cast_frag<<<dim3(320), blk, 0, stream>>>(xl, N_LOW, 125, xl_f, 320, 4);

    // ===================== combined CSR build ===============================
    hipMemsetAsync(cnt, 0, 2 * (size_t)N * sizeof(int), stream);
    hist_all<<<egrid(ETOT), blk, 0, stream>>>(di_lh, di_hh, cnt);
    scan_partial<<<dim3(NB2), blk, 0, stream>>>(cnt, off, bscan, 2 * N);
    scan_bsums<<<dim3(1), blk, 0, stream>>>(bscan, NB2, off, 2 * N);
    scan_add<<<dim3(NB2), blk, 0, stream>>>(off, bscan, 2 * N);
    hipMemcpyAsync(cur, off, 2 * (size_t)N * sizeof(int), hipMemcpyDeviceToDevice, stream);
    scatter_all<<<egrid(ETOT), blk, 0, stream>>>(si_lh, di_lh, si_hh, di_hh, cur, csr);

    // ===================== d layer (low -> high, H=1, C=256) ================
    gemm_mfma<false, true, true><<<dim3(1, 157), blk, 0, stream>>>(xl_f, wf_d, d_bl, hl, N_LOW, 256, 4);
    gat_gather<1, 256, true><<<wgrid(N), blk, 0, stream>>>(
        hl16, nullptr, xh, d_Wr, d_br, rp_lh, csr, d_att, d_b, xA16, 264, 1, N, zstd);

    // ===================== bn0 + frag cast (stride 264, F=257) =============
    hipMemsetAsync(bsum, 0, 528 * sizeof(float), stream);
    bn_partial3<33, 7><<<dim3(RBLK), blk, 0, stream>>>(xA16, N, partials);
    bn_reduce2<<<dim3(9, 32), blk, 0, stream>>>(partials, 528, bsum);
    bn_frag<false><<<dim3(2048), blk, 0, stream>>>(xA16, N, 257, 264, 264, bsum, bn0_g, bn0_b, AfB, NMT, 9);

    // ===================== p1 (H=4, C=64) ===================================
    gemm_mfma2<true><<<dim3(1, 1563, 2), blk, 0, stream>>>(AfB, wf_p1l, wf_p1r, p1_bl, p1_br, hl, hr, N, 256, 9);
    gat_gather<4, 64, false><<<wgrid(N), blk, 0, stream>>>(
        hl16, hr16, nullptr, nullptr, nullptr, rp_hh, csr, p1_att, p1_b, xB16, 256, 0, N, nullptr);
    hipMemsetAsync(bsum, 0, 512 * sizeof(float), stream);
    bn_partial3<32, 8><<<dim3(RBLK), blk, 0, stream>>>(xB16, N, partials);
    bn_reduce2<<<dim3(8, 32), blk, 0, stream>>>(partials, 512, bsum);
    bn_frag<true><<<dim3(2048), blk, 0, stream>>>(xB16, N, 256, 256, 256, bsum, bn1_g, bn1_b, AfA, NMT, 8);

    // ===================== p2 (H=4, C=64) ===================================
    gemm_mfma2<true><<<dim3(1, 1563, 2), blk, 0, stream>>>(AfA, wf_p2l, wf_p2r, p2_bl, p2_br, hl, hr, N, 256, 8);
    gat_gather<4, 64, false><<<wgrid(N), blk, 0, stream>>>(
        hl16, hr16, nullptr, nullptr, nullptr, rp_hh, csr, p2_att, p2_b, xA16, 256, 0, N, nullptr);
    hipMemsetAsync(bsum, 0, 512 * sizeof(float), stream);
    bn_partial3<32, 8><<<dim3(RBLK), blk, 0, stream>>>(xA16, N, partials);
    bn_reduce2<<<dim3(8, 32), blk, 0, stream>>>(partials, 512, bsum);
    bn_frag<true><<<dim3(2048), blk, 0, stream>>>(xA16, N, 256, 256, 256, bsum, bn2_g, bn2_b, AfB, NMT, 8);

    // ===================== p3 (H=1, C=64) ===================================
    gemm_mfma2<false><<<dim3(1, 391, 2), blk, 0, stream>>>(AfB, wf_p3l, wf_p3r, p3_bl, p3_br, hl, hr, N, 64, 8);
    gat_gather<1, 64, false><<<wgrid(N), blk, 0, stream>>>(
        hl16, hr16, nullptr, nullptr, nullptr, rp_hh, csr, p3_att, p3_b, xB16, 64, 0, N, nullptr);
    hipMemsetAsync(bsum, 0, 128 * sizeof(float), stream);
    bn_partial3<8, 32><<<dim3(RBLK), blk, 0, stream>>>(xB16, N, partials);
    bn_reduce2<<<dim3(2, 32), blk, 0, stream>>>(partials, 128, bsum);
    bn_frag<true><<<dim3(2048), blk, 0, stream>>>(xB16, N, 64, 64, 64, bsum, bn3_g, bn3_b, AfA, NMT, 2);

    // ===================== predictor MLP ====================================
    gemm_mfma<true, false, false><<<dim3(1, 391), blk, 0, stream>>>(AfA, wf_pr1, pr_b1, hl, N, 64, 2);
    dot_w2<<<wgrid(N), blk, 0, stream>>>(hl, pr_W2, pr_b2, y, N);
}

// Round 17
// 509.023 us; speedup vs baseline: 1.1126x; 1.0110x over previous
//
#include <hip/hip_runtime.h>
#include <math.h>

#define DEV __device__ __forceinline__

static const int N_LOW = 5000, N_HIGH = 50000, E_LH = 200000, E_HH = 400000;
static const int E2 = E_HH + N_HIGH;   // 450000 with self loops
static const int ETOT = E_LH + E2;     // 650000 combined
static const int RBLK = 2048;          // bn stage-1 blocks
#define LOG2E 1.44269504088896f

typedef __attribute__((ext_vector_type(8))) short bf16x8;
typedef __attribute__((ext_vector_type(4))) float f32x4;
typedef __attribute__((ext_vector_type(2))) float f32x2;
typedef __attribute__((ext_vector_type(8))) unsigned short u16x8;
typedef unsigned short u16;

DEV short f2bf(float v) {            // round-to-nearest-even f32 -> bf16
    unsigned u = __float_as_uint(v);
    u += 0x7FFFu + ((u >> 16) & 1u);
    return (short)(u >> 16);
}
DEV float bf2f(u16 u) { return __uint_as_float(((unsigned)u) << 16); }

template <int VPL> struct RawTT { using T = u16; };
template <> struct RawTT<4> { using T = uint2; };

// =================== MFMA GEMM on fragment-ordered operands =================
// WIDE: one block covers ALL 16 nt tiles (256 cols); wave w owns nt w*4..w*4+3
//       and all waves share the same 2 mt row tiles (A-frags L1-broadcast).
template <bool RELU, bool BF16OUT, bool WIDE>
DEV void gemm_body(const bf16x8* __restrict__ Af, const bf16x8* __restrict__ Bf,
                   const float* __restrict__ bias, float* __restrict__ C,
                   int M, int N, int nkt) {
    const int l = threadIdx.x & 63;
    const int w = threadIdx.x >> 6;
    const int nt0 = WIDE ? w * 4 : blockIdx.x * 4;
    const int mt0 = WIDE ? blockIdx.y * 2 : blockIdx.y * 8 + w * 2;
    f32x4 acc[2][4];
#pragma unroll
    for (int i = 0; i < 2; i++)
#pragma unroll
        for (int j = 0; j < 4; j++) acc[i][j] = (f32x4){0.f, 0.f, 0.f, 0.f};
    const bf16x8* a0p = Af + (size_t)mt0 * nkt * 64 + l;
    const bf16x8* a1p = a0p + (size_t)nkt * 64;
    const bf16x8* bp = Bf + (size_t)nt0 * nkt * 64 + l;
    for (int kt = 0; kt < nkt; kt++) {
        bf16x8 a0 = a0p[kt * 64];
        bf16x8 a1 = a1p[kt * 64];
        bf16x8 b0 = bp[kt * 64];
        bf16x8 b1 = bp[(size_t)(nkt + kt) * 64];
        bf16x8 b2 = bp[(size_t)(2 * nkt + kt) * 64];
        bf16x8 b3 = bp[(size_t)(3 * nkt + kt) * 64];
        acc[0][0] = __builtin_amdgcn_mfma_f32_16x16x32_bf16(a0, b0, acc[0][0], 0, 0, 0);
        acc[0][1] = __builtin_amdgcn_mfma_f32_16x16x32_bf16(a0, b1, acc[0][1], 0, 0, 0);
        acc[0][2] = __builtin_amdgcn_mfma_f32_16x16x32_bf16(a0, b2, acc[0][2], 0, 0, 0);
        acc[0][3] = __builtin_amdgcn_mfma_f32_16x16x32_bf16(a0, b3, acc[0][3], 0, 0, 0);
        acc[1][0] = __builtin_amdgcn_mfma_f32_16x16x32_bf16(a1, b0, acc[1][0], 0, 0, 0);
        acc[1][1] = __builtin_amdgcn_mfma_f32_16x16x32_bf16(a1, b1, acc[1][1], 0, 0, 0);
        acc[1][2] = __builtin_amdgcn_mfma_f32_16x16x32_bf16(a1, b2, acc[1][2], 0, 0, 0);
        acc[1][3] = __builtin_amdgcn_mfma_f32_16x16x32_bf16(a1, b3, acc[1][3], 0, 0, 0);
    }
    const int colb = nt0 * 16 + (l & 15);
    const int rsub = (l >> 4) * 4;
#pragma unroll
    for (int mi = 0; mi < 2; mi++) {
        int rowb = (mt0 + mi) * 16 + rsub;
#pragma unroll
        for (int r = 0; r < 4; r++) {
            int row = rowb + r;
            if (row >= M) continue;
#pragma unroll
            for (int n = 0; n < 4; n++) {
                int col = colb + n * 16;
                float v = acc[mi][n][r] + bias[col];
                if (RELU) v = fmaxf(v, 0.f);
                if (BF16OUT)
                    ((u16*)C)[(size_t)row * N + col] = (u16)f2bf(v);
                else
                    C[(size_t)row * N + col] = v;
            }
        }
    }
}

template <bool RELU, bool BF16OUT, bool WIDE>
__global__ __launch_bounds__(256) void gemm_mfma(
    const bf16x8* __restrict__ Af, const bf16x8* __restrict__ Bf,
    const float* __restrict__ bias, float* __restrict__ C,
    int M, int N, int nkt) {
    gemm_body<RELU, BF16OUT, WIDE>(Af, Bf, bias, C, M, N, nkt);
}

// paired variant: blockIdx.z selects (Bf0,bias0,C0) or (Bf1,bias1,C1); same A.
template <bool WIDE>
__global__ __launch_bounds__(256) void gemm_mfma2(
    const bf16x8* __restrict__ Af,
    const bf16x8* __restrict__ Bf0, const bf16x8* __restrict__ Bf1,
    const float* __restrict__ bias0, const float* __restrict__ bias1,
    float* __restrict__ C0, float* __restrict__ C1,
    int M, int N, int nkt) {
    if (blockIdx.z == 0)
        gemm_body<false, true, WIDE>(Af, Bf0, bias0, C0, M, N, nkt);
    else
        gemm_body<false, true, WIDE>(Af, Bf1, bias1, C1, M, N, nkt);
}

// --------- predictor: y = relu(A@W1 + b1) @ W2 + b2, fused (N=64) ----------
__global__ __launch_bounds__(256) void gemm_pred(
    const bf16x8* __restrict__ Af, const bf16x8* __restrict__ Bf,
    const float* __restrict__ bias, const float* __restrict__ W2,
    const float* __restrict__ b2, float* __restrict__ y, int M, int nkt) {
    const int l = threadIdx.x & 63;
    const int w = threadIdx.x >> 6;
    const int mt0 = blockIdx.y * 8 + w * 2;
    f32x4 acc[2][4];
#pragma unroll
    for (int i = 0; i < 2; i++)
#pragma unroll
        for (int j = 0; j < 4; j++) acc[i][j] = (f32x4){0.f, 0.f, 0.f, 0.f};
    const bf16x8* a0p = Af + (size_t)mt0 * nkt * 64 + l;
    const bf16x8* a1p = a0p + (size_t)nkt * 64;
    const bf16x8* bp = Bf + l;
    for (int kt = 0; kt < nkt; kt++) {
        bf16x8 a0 = a0p[kt * 64];
        bf16x8 a1 = a1p[kt * 64];
        bf16x8 b0 = bp[kt * 64];
        bf16x8 b1 = bp[(size_t)(nkt + kt) * 64];
        bf16x8 b2v = bp[(size_t)(2 * nkt + kt) * 64];
        bf16x8 b3 = bp[(size_t)(3 * nkt + kt) * 64];
        acc[0][0] = __builtin_amdgcn_mfma_f32_16x16x32_bf16(a0, b0, acc[0][0], 0, 0, 0);
        acc[0][1] = __builtin_amdgcn_mfma_f32_16x16x32_bf16(a0, b1, acc[0][1], 0, 0, 0);
        acc[0][2] = __builtin_amdgcn_mfma_f32_16x16x32_bf16(a0, b2v, acc[0][2], 0, 0, 0);
        acc[0][3] = __builtin_amdgcn_mfma_f32_16x16x32_bf16(a0, b3, acc[0][3], 0, 0, 0);
        acc[1][0] = __builtin_amdgcn_mfma_f32_16x16x32_bf16(a1, b0, acc[1][0], 0, 0, 0);
        acc[1][1] = __builtin_amdgcn_mfma_f32_16x16x32_bf16(a1, b1, acc[1][1], 0, 0, 0);
        acc[1][2] = __builtin_amdgcn_mfma_f32_16x16x32_bf16(a1, b2v, acc[1][2], 0, 0, 0);
        acc[1][3] = __builtin_amdgcn_mfma_f32_16x16x32_bf16(a1, b3, acc[1][3], 0, 0, 0);
    }
    const int colb = l & 15;
    const int rsub = (l >> 4) * 4;
    float biasv[4], w2v[4];
#pragma unroll
    for (int n = 0; n < 4; n++) {
        biasv[n] = bias[colb + n * 16];
        w2v[n] = W2[colb + n * 16];
    }
    const float b2s = b2[0];
#pragma unroll
    for (int mi = 0; mi < 2; mi++) {
#pragma unroll
        for (int r = 0; r < 4; r++) {
            int row = (mt0 + mi) * 16 + rsub + r;
            float t = 0.f;
#pragma unroll
            for (int n = 0; n < 4; n++) {
                float v = fmaxf(acc[mi][n][r] + biasv[n], 0.f);
                t = fmaf(v, w2v[n], t);
            }
            t += __shfl_xor(t, 1, 64);
            t += __shfl_xor(t, 2, 64);
            t += __shfl_xor(t, 4, 64);
            t += __shfl_xor(t, 8, 64);
            if ((l & 15) == 0 && row < M) y[row] = t + b2s;
        }
    }
}

// --------- BN-apply (stats from raw sums) + (relu) + bf16 frag cast --------
template <bool RELU>
__global__ __launch_bounds__(256) void bn_frag(
    const u16* __restrict__ x, int Nrows, int F, int STR, int SS,
    const float* __restrict__ sums,
    const float* __restrict__ g, const float* __restrict__ b,
    bf16x8* __restrict__ Af, int nmt, int nkt) {
    int total = nmt * nkt * 64;
    for (int idx = blockIdx.x * blockDim.x + threadIdx.x; idx < total;
         idx += gridDim.x * blockDim.x) {
        int mt = idx / (nkt * 64);
        int rem = idx - mt * (nkt * 64);
        int kt = rem >> 6, l = rem & 63;
        int row = mt * 16 + (l & 15);
        int colb = kt * 32 + (l >> 4) * 8;
        bf16x8 o;
#pragma unroll
        for (int j = 0; j < 8; j++) {
            int col = colb + j;
            float v = 0.f;
            if (row < Nrows && col < F) {
                float mu = sums[col] / Nrows;
                float var = sums[SS + col] / Nrows - mu * mu;
                float istd = rsqrtf(fmaxf(var, 0.f) + 1e-5f);
                v = (bf2f(x[(size_t)row * STR + col]) - mu) * istd * g[col] + b[col];
                if (RELU) v = fmaxf(v, 0.f);
            }
            o[j] = f2bf(v);
        }
        Af[idx] = o;
    }
}

// --------- ALL weight/xl -> fragment transforms in one kernel --------------
// isA: 0 = weight [K][N] -> B-frags; 1 = activation f32 [Nrows][F] -> A-frags.
struct WtJobs {
    const float* W[9];
    bf16x8* out[9];
    int K[9], Nn[9], nnt[9], nkt[9], isA[9];
};
__global__ __launch_bounds__(256) void wt_frag_all(WtJobs jobs) {
    const int job = blockIdx.y;
    const float* W = jobs.W[job];
    bf16x8* Bf = jobs.out[job];
    const int K = jobs.K[job], N = jobs.Nn[job];
    const int nkt = jobs.nkt[job];
    const bool isA = jobs.isA[job] != 0;
    int total = jobs.nnt[job] * nkt * 64;
    for (int idx = blockIdx.x * blockDim.x + threadIdx.x; idx < total;
         idx += gridDim.x * blockDim.x) {
        int nt = idx / (nkt * 64);
        int rem = idx - nt * (nkt * 64);
        int kt = rem >> 6, l = rem & 63;
        bf16x8 o;
        if (!isA) {
            int col = nt * 16 + (l & 15);
            int kb = kt * 32 + (l >> 4) * 8;
#pragma unroll
            for (int j = 0; j < 8; j++) {
                int k = kb + j;
                o[j] = (k < K && col < N) ? f2bf(W[(size_t)k * N + col]) : (short)0;
            }
        } else {       // A: K = F (cols), N = Nrows
            int row = nt * 16 + (l & 15);
            int colb = kt * 32 + (l >> 4) * 8;
#pragma unroll
            for (int j = 0; j < 8; j++) {
                int col = colb + j;
                o[j] = (row < N && col < K) ? f2bf(W[(size_t)row * K + col]) : (short)0;
            }
        }
        Bf[idx] = o;
    }
}

// ------------- combined CSR build over BOTH edge sets ----------------------
__global__ __launch_bounds__(256) void hist_all(
    const int* __restrict__ di_lh, const int* __restrict__ di_hh,
    int* __restrict__ cnt) {
    for (int i = blockIdx.x * blockDim.x + threadIdx.x; i < ETOT;
         i += gridDim.x * blockDim.x) {
        if (i < E_LH) {
            atomicAdd(&cnt[di_lh[i]], 1);
        } else {
            int j = i - E_LH;
            int d = (j < E_HH) ? di_hh[j] : (j - E_HH);
            atomicAdd(&cnt[N_HIGH + d], 1);
        }
    }
}

// ---- parallel exclusive scan over n ints (3 kernels, chunks of 1024) -------
__global__ __launch_bounds__(256) void scan_partial(
    const int* __restrict__ cnt, int* __restrict__ off,
    int* __restrict__ bsum, int n) {
    __shared__ int s[256];
    const int t = threadIdx.x;
    const int base = blockIdx.x * 1024 + t * 4;
    int v0 = (base < n) ? cnt[base] : 0;
    int v1 = (base + 1 < n) ? cnt[base + 1] : 0;
    int v2 = (base + 2 < n) ? cnt[base + 2] : 0;
    int v3 = (base + 3 < n) ? cnt[base + 3] : 0;
    int tsum = v0 + v1 + v2 + v3;
    s[t] = tsum;
    __syncthreads();
    for (int step = 1; step < 256; step <<= 1) {
        int q = (t >= step) ? s[t - step] : 0;
        __syncthreads();
        s[t] += q;
        __syncthreads();
    }
    int excl = s[t] - tsum;
    if (base < n) off[base] = excl;
    if (base + 1 < n) off[base + 1] = excl + v0;
    if (base + 2 < n) off[base + 2] = excl + v0 + v1;
    if (base + 3 < n) off[base + 3] = excl + v0 + v1 + v2;
    if (t == 255) bsum[blockIdx.x] = s[255];
}

__global__ __launch_bounds__(256) void scan_bsums(
    int* __restrict__ bsum, int nb, int* __restrict__ off, int n) {
    __shared__ int s[256];
    const int t = threadIdx.x;
    int v = (t < nb) ? bsum[t] : 0;
    s[t] = v;
    __syncthreads();
    for (int step = 1; step < 256; step <<= 1) {
        int q = (t >= step) ? s[t - step] : 0;
        __syncthreads();
        s[t] += q;
        __syncthreads();
    }
    if (t < nb) bsum[t] = s[t] - v;          // exclusive
    if (t == 255) off[n] = s[255];           // grand total
}

__global__ __launch_bounds__(256) void scan_add(
    int* __restrict__ off, const int* __restrict__ bsum, int n) {
    int b = blockIdx.x;
    int add = bsum[b];
    int base = b * 1024;
    int end = base + 1024 < n ? base + 1024 : n;
    for (int i = base + threadIdx.x; i < end; i += 256) off[i] += add;
}

__global__ __launch_bounds__(256) void scatter_all(
    const int* __restrict__ si_lh, const int* __restrict__ di_lh,
    const int* __restrict__ si_hh, const int* __restrict__ di_hh,
    int* __restrict__ cur, int* __restrict__ csr) {
    for (int i = blockIdx.x * blockDim.x + threadIdx.x; i < ETOT;
         i += gridDim.x * blockDim.x) {
        int d, s, bucket;
        if (i < E_LH) {
            d = di_lh[i]; s = si_lh[i]; bucket = d;
        } else {
            int j = i - E_LH;
            if (j < E_HH) { d = di_hh[j]; s = si_hh[j]; }
            else { d = s = j - E_HH; }
            bucket = N_HIGH + d;
        }
        int p = atomicAdd(&cur[bucket], 1);
        csr[p] = s;
    }
}

// ---------- fused GATv2 (bf16 hl/hr, bf16 out) ------------------------------
// VPL==4 path uses packed f32x2 math (v_pk_*) and exp2-domain softmax
// (att pre-scaled by log2e -> native v_exp_f32 without per-edge mul).
template <int H, int C, bool HR_ONFLY>
__global__ __launch_bounds__(256) void gat_gather(
    const u16* __restrict__ hl, const u16* __restrict__ hr,
    const float* __restrict__ xh, const float* __restrict__ Wr,
    const float* __restrict__ br,
    const int* __restrict__ rowptr, const int* __restrict__ csr_src,
    const float* __restrict__ att, const float* __restrict__ bias,
    u16* __restrict__ out, int outStride, int outOfs, int Ndst,
    const float* __restrict__ col0) {
    constexpr int HC = H * C;
    constexpr int VPL = HC / 64;
    constexpr int LPH = C / VPL;
    using RawT = typename RawTT<VPL>::T;
    int w = blockIdx.x * (blockDim.x >> 6) + (threadIdx.x >> 6);
    if (w >= Ndst) return;
    const int l = threadIdx.x & 63;

    const int e0 = rowptr[w], e1 = rowptr[w + 1];
    float m = -3.4e38f, s = 0.f;
    float accout[VPL];

    if constexpr (VPL == 4) {
        f32x2 hr2[2], at2[2];
        if constexpr (HR_ONFLY) {
            float xv = xh[w];
            float4 wr = *reinterpret_cast<const float4*>(Wr + l * 4);
            float4 bb = *reinterpret_cast<const float4*>(br + l * 4);
            hr2[0].x = fmaf(xv, wr.x, bb.x); hr2[0].y = fmaf(xv, wr.y, bb.y);
            hr2[1].x = fmaf(xv, wr.z, bb.z); hr2[1].y = fmaf(xv, wr.w, bb.w);
        } else {
            uint2 tt = *(reinterpret_cast<const uint2*>(hr + (size_t)w * HC) + l);
            hr2[0].x = __uint_as_float(tt.x << 16);
            hr2[0].y = __uint_as_float(tt.x & 0xFFFF0000u);
            hr2[1].x = __uint_as_float(tt.y << 16);
            hr2[1].y = __uint_as_float(tt.y & 0xFFFF0000u);
        }
        {
            float4 u = *reinterpret_cast<const float4*>(att + l * 4);
            at2[0].x = u.x * LOG2E; at2[0].y = u.y * LOG2E;
            at2[1].x = u.z * LOG2E; at2[1].y = u.w * LOG2E;
        }
        f32x2 acc2[2] = {{0.f, 0.f}, {0.f, 0.f}};

        auto proc = [&](uint2 tt) {
            f32x2 h0, h1;
            h0.x = __uint_as_float(tt.x << 16);
            h0.y = __uint_as_float(tt.x & 0xFFFF0000u);
            h1.x = __uint_as_float(tt.y << 16);
            h1.y = __uint_as_float(tt.y & 0xFFFF0000u);
            f32x2 z0 = h0 + hr2[0];
            f32x2 z1 = h1 + hr2[1];
            z0 = __builtin_elementwise_max(z0, z0 * 0.2f);
            z1 = __builtin_elementwise_max(z1, z1 * 0.2f);
            f32x2 v2 = z0 * at2[0];
            v2 = __builtin_elementwise_fma(z1, at2[1], v2);
            float v = v2.x + v2.y;
#pragma unroll
            for (int t2 = 1; t2 < LPH; t2 <<= 1) v += __shfl_xor(v, t2, 64);
            float d = v - m;
            bool up = d > 0.f;
            float ef = exp2f(-fabsf(d));     // native v_exp_f32
            float sc = up ? ef : 1.f;
            float p  = up ? 1.f : ef;
            m = up ? v : m;
            s = fmaf(s, sc, p);
            f32x2 sc2; sc2.x = sc; sc2.y = sc;
            f32x2 p2;  p2.x = p;  p2.y = p;
            acc2[0] = __builtin_elementwise_fma(acc2[0], sc2, h0 * p2);
            acc2[1] = __builtin_elementwise_fma(acc2[1], sc2, h1 * p2);
        };

        int e = e0;
        for (; e + 3 < e1; e += 4) {
            int sv0 = csr_src[e];
            int sv1 = csr_src[e + 1];
            int sv2 = csr_src[e + 2];
            int sv3 = csr_src[e + 3];
            uint2 t0 = *(reinterpret_cast<const uint2*>(hl + (size_t)sv0 * HC) + l);
            uint2 t1 = *(reinterpret_cast<const uint2*>(hl + (size_t)sv1 * HC) + l);
            uint2 t2 = *(reinterpret_cast<const uint2*>(hl + (size_t)sv2 * HC) + l);
            uint2 t3 = *(reinterpret_cast<const uint2*>(hl + (size_t)sv3 * HC) + l);
            proc(t0); proc(t1); proc(t2); proc(t3);
        }
        for (; e < e1; e++) {
            uint2 t = *(reinterpret_cast<const uint2*>(hl + (size_t)csr_src[e] * HC) + l);
            proc(t);
        }
        accout[0] = acc2[0].x; accout[1] = acc2[0].y;
        accout[2] = acc2[1].x; accout[3] = acc2[1].y;
    } else {
        float hrv = bf2f(hr[(size_t)w * HC + l]);
        float attv = att[l] * LOG2E;
        float acc = 0.f;
        auto proc = [&](u16 t) {
            float hlv = bf2f(t);
            float z = hlv + hrv;
            float v = fmaxf(z, 0.2f * z) * attv;
#pragma unroll
            for (int t2 = 1; t2 < LPH; t2 <<= 1) v += __shfl_xor(v, t2, 64);
            float d = v - m;
            bool up = d > 0.f;
            float ef = exp2f(-fabsf(d));
            float sc = up ? ef : 1.f;
            float p  = up ? 1.f : ef;
            m = up ? v : m;
            s = fmaf(s, sc, p);
            acc = fmaf(acc, sc, p * hlv);
        };
        int e = e0;
        for (; e + 3 < e1; e += 4) {
            int sv0 = csr_src[e];
            int sv1 = csr_src[e + 1];
            int sv2 = csr_src[e + 2];
            int sv3 = csr_src[e + 3];
            u16 t0 = hl[(size_t)sv0 * HC + l];
            u16 t1 = hl[(size_t)sv1 * HC + l];
            u16 t2 = hl[(size_t)sv2 * HC + l];
            u16 t3 = hl[(size_t)sv3 * HC + l];
            proc(t0); proc(t1); proc(t2); proc(t3);
        }
        for (; e < e1; e++) proc(hl[(size_t)csr_src[e] * HC + l]);
        accout[0] = acc;
    }

    float inv = 1.f / (s + 1e-16f);
    float dnorm = inv / fmaxf((float)(e1 - e0), 1.f);
    if constexpr (VPL == 4) {
        if (((outOfs | outStride) & 3) == 0) {
            ushort4 o;
            o.x = (u16)f2bf(accout[0] * dnorm + bias[l * 4 + 0]);
            o.y = (u16)f2bf(accout[1] * dnorm + bias[l * 4 + 1]);
            o.z = (u16)f2bf(accout[2] * dnorm + bias[l * 4 + 2]);
            o.w = (u16)f2bf(accout[3] * dnorm + bias[l * 4 + 3]);
            *(reinterpret_cast<ushort4*>(out + (size_t)w * outStride + outOfs) + l) = o;
        } else {
#pragma unroll
            for (int j = 0; j < 4; j++)
                out[(size_t)w * outStride + outOfs + l * 4 + j] =
                    (u16)f2bf(accout[j] * dnorm + bias[l * 4 + j]);
        }
    } else {
        out[(size_t)w * outStride + outOfs + l] =
            (u16)f2bf(accout[0] * dnorm + bias[l]);
    }
    if (col0 && l == 0) out[(size_t)w * outStride] = (u16)f2bf(col0[w]);
}

// ----------- BN stats stage 1: ushort8 loads, LDS reduce, no atomics -------
template <int NC, int RPB>
__global__ __launch_bounds__(256) void bn_partial3(
    const u16* __restrict__ x, int Nrows, float* __restrict__ partials) {
    constexpr int STR = NC * 8;
    constexpr int NSTAT = 2 * NC * 8;
    const int t = threadIdx.x;
    const int b = blockIdx.x;
    __shared__ float l1[NC * RPB * 8];
    __shared__ float l2[NC * RPB * 8];
    float s1[8] = {}, s2[8] = {};
    if (t < NC * RPB) {
        const int rg = t / NC, cg = t - (t / NC) * NC;
        for (int r = b * RPB + rg; r < Nrows; r += RBLK * RPB) {
            u16x8 p = *reinterpret_cast<const u16x8*>(x + (size_t)r * STR + cg * 8);
#pragma unroll
            for (int j = 0; j < 8; j++) {
                float v = bf2f(p[j]);
                s1[j] += v; s2[j] += v * v;
            }
        }
#pragma unroll
        for (int j = 0; j < 8; j++) {
            l1[t * 8 + j] = s1[j];
            l2[t * 8 + j] = s2[j];
        }
    }
    __syncthreads();
    if (t < NC) {
        float a[8] = {}, c[8] = {};
#pragma unroll
        for (int rg = 0; rg < RPB; rg++)
#pragma unroll
            for (int j = 0; j < 8; j++) {
                a[j] += l1[(rg * NC + t) * 8 + j];
                c[j] += l2[(rg * NC + t) * 8 + j];
            }
#pragma unroll
        for (int j = 0; j < 8; j++) {
            partials[(size_t)b * NSTAT + t * 8 + j] = a[j];
            partials[(size_t)b * NSTAT + NC * 8 + t * 8 + j] = c[j];
        }
    }
}

// ----------- BN stats stage 2: 2D grid, coalesced, few atomics -------------
__global__ __launch_bounds__(256) void bn_reduce2(
    const float* __restrict__ partials, int nstat, float* __restrict__ bsum) {
    const int sl = threadIdx.x & 63, ch = threadIdx.x >> 6;
    const int s = blockIdx.x * 64 + sl;
    const int b0 = blockIdx.y * (RBLK / 32);
    float v = 0.f;
    if (s < nstat) {
        for (int b = b0 + ch; b < b0 + RBLK / 32; b += 4)
            v += partials[(size_t)b * nstat + s];
    }
    __shared__ float l[256];
    l[threadIdx.x] = v;
    __syncthreads();
    if (ch == 0 && s < nstat)
        atomicAdd(&bsum[s], l[sl] + l[sl + 64] + l[sl + 128] + l[sl + 192]);
}

// ---------------------------------------------------------------------------
extern "C" void kernel_launch(void* const* d_in, const int* in_sizes, int n_in,
                              void* d_out, int out_size, void* d_ws, size_t ws_size,
                              hipStream_t stream) {
    const float* xl   = (const float*)d_in[0];
    const float* xh   = (const float*)d_in[1];
    const float* zstd = (const float*)d_in[2];
    const int* si_lh  = (const int*)d_in[3];
    const int* di_lh  = (const int*)d_in[4];
    const int* si_hh  = (const int*)d_in[5];
    const int* di_hh  = (const int*)d_in[6];
    int a = 7;
    const float *d_Wl = (const float*)d_in[a++], *d_bl = (const float*)d_in[a++],
                *d_Wr = (const float*)d_in[a++], *d_br = (const float*)d_in[a++],
                *d_att = (const float*)d_in[a++], *d_b = (const float*)d_in[a++];
    const float *p1_Wl = (const float*)d_in[a++], *p1_bl = (const float*)d_in[a++],
                *p1_Wr = (const float*)d_in[a++], *p1_br = (const float*)d_in[a++],
                *p1_att = (const float*)d_in[a++], *p1_b = (const float*)d_in[a++];
    const float *p2_Wl = (const float*)d_in[a++], *p2_bl = (const float*)d_in[a++],
                *p2_Wr = (const float*)d_in[a++], *p2_br = (const float*)d_in[a++],
                *p2_att = (const float*)d_in[a++], *p2_b = (const float*)d_in[a++];
    const float *p3_Wl = (const float*)d_in[a++], *p3_bl = (const float*)d_in[a++],
                *p3_Wr = (const float*)d_in[a++], *p3_br = (const float*)d_in[a++],
                *p3_att = (const float*)d_in[a++], *p3_b = (const float*)d_in[a++];
    const float *bn0_g = (const float*)d_in[a++], *bn0_b = (const float*)d_in[a++],
                *bn1_g = (const float*)d_in[a++], *bn1_b = (const float*)d_in[a++],
                *bn2_g = (const float*)d_in[a++], *bn2_b = (const float*)d_in[a++],
                *bn3_g = (const float*)d_in[a++], *bn3_b = (const float*)d_in[a++];
    const float *pr_W1 = (const float*)d_in[a++], *pr_b1 = (const float*)d_in[a++],
                *pr_W2 = (const float*)d_in[a++], *pr_b2 = (const float*)d_in[a++];
    float* y = (float*)d_out;

    const int N = N_HIGH;
    const int NMT = 3125;                    // 50000/16
    const int NB2 = (2 * N + 1023) / 1024;   // scan blocks over 2N = 98
    // ---- workspace layout ----
    float* ws = (float*)d_ws;
    float* xA = ws;                           // region 50000*257 f32 (bf16 stride-264 used / hosts AfA)
    float* xB = xA + (size_t)N * 257;         // region 50000*256 f32 (bf16 used / hosts AfB)
    float* hl = xB + (size_t)N * 256;         // 50000*256 (bf16 used)
    float* hr = hl + (size_t)N * 256;         // 50000*256 (bf16 used; dead during BN -> partials)
    bf16x8* xl_f = (bf16x8*)(hr + (size_t)N * 256);   // 320*4*64 frags
    bf16x8* wf_d   = xl_f + 320 * 4 * 64;     // 16*4*64
    bf16x8* wf_p1l = wf_d + 16 * 4 * 64;      // 16*9*64
    bf16x8* wf_p1r = wf_p1l + 16 * 9 * 64;
    bf16x8* wf_p2l = wf_p1r + 16 * 9 * 64;    // 16*8*64
    bf16x8* wf_p2r = wf_p2l + 16 * 8 * 64;
    bf16x8* wf_p3l = wf_p2r + 16 * 8 * 64;    // 4*8*64
    bf16x8* wf_p3r = wf_p3l + 4 * 8 * 64;
    bf16x8* wf_pr1 = wf_p3r + 4 * 8 * 64;     // 4*2*64
    float* bsum = (float*)(wf_pr1 + 4 * 2 * 64); // 4 slots x 544
    int* bscan  = (int*)(bsum + 4 * 544);     // 256
    int* cnt    = bscan + 256;                // 2N
    int* off    = cnt + 2 * N;                // 2N+1
    int* cur    = off + 2 * N + 1;            // 2N
    int* csr    = cur + 2 * N;                // 650000
    size_t need = (size_t)((char*)(csr + ETOT) - (char*)ws);
    if (ws_size < need) return;
    bf16x8* AfB = (bf16x8*)xB;
    bf16x8* AfA = (bf16x8*)xA;
    u16* xA16 = (u16*)xA;        // stride-264 bf16 rows
    u16* xB16 = (u16*)xB;
    u16* hl16 = (u16*)hl;
    u16* hr16 = (u16*)hr;
    float* partials = hr;        // overlay: hr region dead during BN stats
    int* rp_lh = off;
    int* rp_hh = off + N;

    dim3 blk(256);
    auto wgrid = [](int E) { return dim3((E + 3) / 4); };
    auto egrid = [](size_t total) {
        size_t g = (total + 255) / 256;
        return dim3((unsigned)(g > 2048 ? 2048 : g));
    };

    // ===================== fragment transforms (one kernel, 9 jobs) =========
    WtJobs jobs;
    jobs.W[0] = d_Wl;  jobs.out[0] = wf_d;   jobs.K[0] = 125; jobs.Nn[0] = 256; jobs.nnt[0] = 16; jobs.nkt[0] = 4; jobs.isA[0] = 0;
    jobs.W[1] = p1_Wl; jobs.out[1] = wf_p1l; jobs.K[1] = 257; jobs.Nn[1] = 256; jobs.nnt[1] = 16; jobs.nkt[1] = 9; jobs.isA[1] = 0;
    jobs.W[2] = p1_Wr; jobs.out[2] = wf_p1r; jobs.K[2] = 257; jobs.Nn[2] = 256; jobs.nnt[2] = 16; jobs.nkt[2] = 9; jobs.isA[2] = 0;
    jobs.W[3] = p2_Wl; jobs.out[3] = wf_p2l; jobs.K[3] = 256; jobs.Nn[3] = 256; jobs.nnt[3] = 16; jobs.nkt[3] = 8; jobs.isA[3] = 0;
    jobs.W[4] = p2_Wr; jobs.out[4] = wf_p2r; jobs.K[4] = 256; jobs.Nn[4] = 256; jobs.nnt[4] = 16; jobs.nkt[4] = 8; jobs.isA[4] = 0;
    jobs.W[5] = p3_Wl; jobs.out[5] = wf_p3l; jobs.K[5] = 256; jobs.Nn[5] = 64;  jobs.nnt[5] = 4;  jobs.nkt[5] = 8; jobs.isA[5] = 0;
    jobs.W[6] = p3_Wr; jobs.out[6] = wf_p3r; jobs.K[6] = 256; jobs.Nn[6] = 64;  jobs.nnt[6] = 4;  jobs.nkt[6] = 8; jobs.isA[6] = 0;
    jobs.W[7] = pr_W1; jobs.out[7] = wf_pr1; jobs.K[7] = 64;  jobs.Nn[7] = 64;  jobs.nnt[7] = 4;  jobs.nkt[7] = 2; jobs.isA[7] = 0;
    jobs.W[8] = xl;    jobs.out[8] = xl_f;   jobs.K[8] = 125; jobs.Nn[8] = N_LOW; jobs.nnt[8] = 320; jobs.nkt[8] = 4; jobs.isA[8] = 1;
    wt_frag_all<<<dim3(36, 9), blk, 0, stream>>>(jobs);

    // ===================== single memset: 4 bsum slots + bscan + cnt ========
    hipMemsetAsync(bsum, 0, (4 * 544 + 256 + 2 * (size_t)N) * sizeof(float), stream);

    // ===================== combined CSR build ===============================
    hist_all<<<egrid(ETOT), blk, 0, stream>>>(di_lh, di_hh, cnt);
    scan_partial<<<dim3(NB2), blk, 0, stream>>>(cnt, off, bscan, 2 * N);
    scan_bsums<<<dim3(1), blk, 0, stream>>>(bscan, NB2, off, 2 * N);
    scan_add<<<dim3(NB2), blk, 0, stream>>>(off, bscan, 2 * N);
    hipMemcpyAsync(cur, off, 2 * (size_t)N * sizeof(int), hipMemcpyDeviceToDevice, stream);
    scatter_all<<<egrid(ETOT), blk, 0, stream>>>(si_lh, di_lh, si_hh, di_hh, cur, csr);

    // ===================== d layer (low -> high, H=1, C=256) ================
    gemm_mfma<false, true, true><<<dim3(1, 157), blk, 0, stream>>>(xl_f, wf_d, d_bl, hl, N_LOW, 256, 4);
    gat_gather<1, 256, true><<<wgrid(N), blk, 0, stream>>>(
        hl16, nullptr, xh, d_Wr, d_br, rp_lh, csr, d_att, d_b, xA16, 264, 1, N, zstd);

    // ===================== bn0 + frag cast (stride 264, F=257) =============
    bn_partial3<33, 7><<<dim3(RBLK), blk, 0, stream>>>(xA16, N, partials);
    bn_reduce2<<<dim3(9, 32), blk, 0, stream>>>(partials, 528, bsum);
    bn_frag<false><<<dim3(2048), blk, 0, stream>>>(xA16, N, 257, 264, 264, bsum, bn0_g, bn0_b, AfB, NMT, 9);

    // ===================== p1 (H=4, C=64) ===================================
    gemm_mfma2<true><<<dim3(1, 1563, 2), blk, 0, stream>>>(AfB, wf_p1l, wf_p1r, p1_bl, p1_br, hl, hr, N, 256, 9);
    gat_gather<4, 64, false><<<wgrid(N), blk, 0, stream>>>(
        hl16, hr16, nullptr, nullptr, nullptr, rp_hh, csr, p1_att, p1_b, xB16, 256, 0, N, nullptr);
    bn_partial3<32, 8><<<dim3(RBLK), blk, 0, stream>>>(xB16, N, partials);
    bn_reduce2<<<dim3(8, 32), blk, 0, stream>>>(partials, 512, bsum + 544);
    bn_frag<true><<<dim3(2048), blk, 0, stream>>>(xB16, N, 256, 256, 256, bsum + 544, bn1_g, bn1_b, AfA, NMT, 8);

    // ===================== p2 (H=4, C=64) ===================================
    gemm_mfma2<true><<<dim3(1, 1563, 2), blk, 0, stream>>>(AfA, wf_p2l, wf_p2r, p2_bl, p2_br, hl, hr, N, 256, 8);
    gat_gather<4, 64, false><<<wgrid(N), blk, 0, stream>>>(
        hl16, hr16, nullptr, nullptr, nullptr, rp_hh, csr, p2_att, p2_b, xA16, 256, 0, N, nullptr);
    bn_partial3<32, 8><<<dim3(RBLK), blk, 0, stream>>>(xA16, N, partials);
    bn_reduce2<<<dim3(8, 32), blk, 0, stream>>>(partials, 512, bsum + 2 * 544);
    bn_frag<true><<<dim3(2048), blk, 0, stream>>>(xA16, N, 256, 256, 256, bsum + 2 * 544, bn2_g, bn2_b, AfB, NMT, 8);

    // ===================== p3 (H=1, C=64) ===================================
    gemm_mfma2<false><<<dim3(1, 391, 2), blk, 0, stream>>>(AfB, wf_p3l, wf_p3r, p3_bl, p3_br, hl, hr, N, 64, 8);
    gat_gather<1, 64, false><<<wgrid(N), blk, 0, stream>>>(
        hl16, hr16, nullptr, nullptr, nullptr, rp_hh, csr, p3_att, p3_b, xB16, 64, 0, N, nullptr);
    bn_partial3<8, 32><<<dim3(RBLK), blk, 0, stream>>>(xB16, N, partials);
    bn_reduce2<<<dim3(2, 32), blk, 0, stream>>>(partials, 128, bsum + 3 * 544);
    bn_frag<true><<<dim3(2048), blk, 0, stream>>>(xB16, N, 64, 64, 64, bsum + 3 * 544, bn3_g, bn3_b, AfA, NMT, 2);

    // ===================== predictor MLP (fused GEMM + W2 dot) ==============
    gemm_pred<<<dim3(1, 391), blk, 0, stream>>>(AfA, wf_pr1, pr_b1, pr_W2, pr_b2, y, N, 2);
}